// Round 7
// baseline (628.700 us; speedup 1.0000x reference)
//
#include <hip/hip_runtime.h>

#define NP 2048
#define BATCH 8
#define KNN 40
#define EPSF 1e-6f
#define BNEPS 1e-5f

typedef __attribute__((ext_vector_type(8))) short short8;
typedef __attribute__((ext_vector_type(4))) float f32x4;

__device__ __forceinline__ unsigned ordf(float v){
  unsigned u = __float_as_uint(v);
  return (u & 0x80000000u) ? ~u : (u | 0x80000000u);
}

// split fp32 -> bf16 hi (RNE) + bf16 lo (RNE of residual)
__device__ __forceinline__ void bsplit(float v, unsigned short &h, unsigned short &l){
  unsigned u = __float_as_uint(v);
  unsigned hu = (u + 0x7fffu + ((u >> 16) & 1u)) >> 16;
  h = (unsigned short)hu;
  float r = v - __uint_as_float(hu << 16);
  unsigned u2 = __float_as_uint(r);
  l = (unsigned short)((u2 + 0x7fffu + ((u2 >> 16) & 1u)) >> 16);
}

__device__ __forceinline__ float bf2f(unsigned short h){
  return __uint_as_float(((unsigned)h) << 16);
}

// ---------------- KNN: exact top-40 (nearest incl. self), tie -> lowest index ----------
// One wave per (b,i). LDS float4 (x,y,z,|x|^2); per-lane top-4 cache; 32-bit pop reduce.
// Writes idx [row][k] (for gf_stats) AND idxT [k][row] (for gf_applypool2).
__global__ __launch_bounds__(256) void knn_kernel(const float* __restrict__ x, int* __restrict__ idx,
                                                  int* __restrict__ idxT){
  __shared__ float4 sP[NP];   // 32 KB
  int tid = threadIdx.x;
  int w = tid >> 6, lane = tid & 63;
  int row = blockIdx.x * 4 + w;
  int b = row >> 11, i = row & 2047;
  const float* xb = x + b * 3 * NP;
  for (int t = tid; t < NP; t += 256){
    float a = xb[t], c = xb[NP + t], d = xb[2*NP + t];
    float xx = __fadd_rn(__fadd_rn(__fmul_rn(a,a), __fmul_rn(c,c)), __fmul_rn(d,d));
    sP[t] = make_float4(a, c, d, xx);
  }
  __syncthreads();
  float4 pi = sP[i];
  const float4* lp = &sP[lane];
  unsigned long long s0 = 0, s1 = 0, s2 = 0, s3 = 0;
  #pragma unroll
  for (int m = 0; m < 32; m++){
    float4 pj = lp[m * 64];
    float dot = __fadd_rn(__fadd_rn(__fmul_rn(pi.x, pj.x), __fmul_rn(pi.y, pj.y)), __fmul_rn(pi.z, pj.z));
    float v = __fsub_rn(__fsub_rn(-pi.w, __fmul_rn(-2.f, dot)), pj.w);
    unsigned long long pk = ((unsigned long long)ordf(v) << 32) | (unsigned)(2047 - (m*64 + lane));
    if (pk > s3){
      if (pk > s2){ s3 = s2; if (pk > s1){ s2 = s1; if (pk > s0){ s1 = s0; s0 = pk; } else s1 = pk; } else s2 = pk; }
      else s3 = pk;
    }
  }
  unsigned myout = 0;
  unsigned long long lastPop = ~0ull;
  for (int kk = 0; kk < KNN; kk++){
    unsigned hv = (unsigned)(s0 >> 32);
    unsigned vm = hv;
    #pragma unroll
    for (int st = 32; st > 0; st >>= 1){
      unsigned o = (unsigned)__shfl_xor((int)vm, st, 64);
      vm = (o > vm) ? o : vm;
    }
    bool cand = (hv == vm);
    unsigned long long msk = __ballot(cand);
    unsigned lo;
    if (__popcll(msk) == 1){
      int wl = __ffsll((unsigned long long)msk) - 1;
      lo = (unsigned)__shfl((int)(unsigned)s0, wl, 64);
    } else {
      unsigned cl = cand ? (unsigned)s0 : 0u;
      #pragma unroll
      for (int st = 32; st > 0; st >>= 1){
        unsigned o = (unsigned)__shfl_xor((int)cl, st, 64);
        cl = (o > cl) ? o : cl;
      }
      lo = cl;
    }
    if (lane == kk) myout = lo;
    if (cand && (unsigned)s0 == lo){
      lastPop = s0;
      s0 = s1; s1 = s2; s2 = s3; s3 = 0;
      if (s0 == 0){
        unsigned long long best = 0;
        #pragma unroll
        for (int m = 0; m < 32; m++){
          float4 pj = lp[m * 64];
          float dot = __fadd_rn(__fadd_rn(__fmul_rn(pi.x, pj.x), __fmul_rn(pi.y, pj.y)), __fmul_rn(pi.z, pj.z));
          float v = __fsub_rn(__fsub_rn(-pi.w, __fmul_rn(-2.f, dot)), pj.w);
          unsigned long long pk = ((unsigned long long)ordf(v) << 32) | (unsigned)(2047 - (m*64 + lane));
          if (pk < lastPop && pk > best) best = pk;
        }
        s0 = best;
      }
    }
  }
  if (lane < KNN){
    int v = 2047 - (int)myout;
    idx[row * KNN + lane] = v;
    idxT[lane * (BATCH*NP) + row] = v;
  }
}

// ------------- graph-feature layer: stats pass (p-norm sums per channel, 21 ch) --------
__global__ __launch_bounds__(256) void gf_stats(const float* __restrict__ x, const int* __restrict__ idx,
                                                const float* __restrict__ Wf, double* __restrict__ sums){
  int tid0 = blockIdx.x * 256 + threadIdx.x;
  float s[21], q[21];
  #pragma unroll
  for (int o = 0; o < 21; o++){ s[o] = 0.f; q[o] = 0.f; }
  for (int pix = tid0; pix < BATCH * NP * KNN; pix += 256 * 256){
    int rem = pix / KNN;
    int n = rem & 2047, b = rem >> 11;
    int j = idx[pix];
    const float* xb = x + b * 3 * NP;
    float c0 = xb[n], c1 = xb[NP + n], c2 = xb[2*NP + n];
    float a0 = xb[j], a1 = xb[NP + j], a2 = xb[2*NP + j];
    float r0 = a0 - c0, r1 = a1 - c1, r2 = a2 - c2;
    float g0 = a1*c2 - a2*c1, g1 = a2*c0 - a0*c2, g2 = a0*c1 - a1*c0;
    #pragma unroll
    for (int o = 0; o < 21; o++){
      float w0 = Wf[o*3], w1 = Wf[o*3+1], w2 = Wf[o*3+2];
      float p0 = w0*r0 + w1*c0 + w2*g0;
      float p1 = w0*r1 + w1*c1 + w2*g1;
      float p2 = w0*r2 + w1*c2 + w2*g2;
      float nm = sqrtf(p0*p0 + p1*p1 + p2*p2) + EPSF;
      s[o] += nm; q[o] += nm * nm;
    }
  }
  __shared__ float bs[4][42];
  int w = threadIdx.x >> 6;
  #pragma unroll
  for (int o = 0; o < 21; o++){
    float a = s[o], bb = q[o];
    #pragma unroll
    for (int st = 1; st < 64; st <<= 1){ a += __shfl_xor(a, st, 64); bb += __shfl_xor(bb, st, 64); }
    if ((threadIdx.x & 63) == 0){ bs[w][o] = a; bs[w][21 + o] = bb; }
  }
  __syncthreads();
  if (threadIdx.x < 42){
    float tot = bs[0][threadIdx.x] + bs[1][threadIdx.x] + bs[2][threadIdx.x] + bs[3][threadIdx.x];
    int o = threadIdx.x % 21, sq = threadIdx.x / 21;
    atomicAdd(&sums[2*o + sq], (double)tot);
  }
}

// -------- graph-feature layer: apply bn+lrelu + K-pool, thread = (pixel, k-chunk) ------
// 8 threads per pixel, 5 neighbors each; packed u64 argmax (tie -> lowest k);
// combine via 3 shfl_xor; winners recomputed from LDS; lane kc==0 stores.
#define KSPLIT 8
#define KPER 5
__global__ __launch_bounds__(256) void gf_applypool2(const float* __restrict__ x, const int* __restrict__ idxT,
    const float* __restrict__ Wf, const float* __restrict__ Wd, const float* __restrict__ Wg,
    const float* __restrict__ mi, float* __restrict__ h1){
  __shared__ float4 sP[NP];   // 32 KB
  const int tid = threadIdx.x;
  const int pxl = tid >> 3, kc = tid & 7;
  const int px = blockIdx.x * 32 + pxl;
  const int b = px >> 11, n = px & 2047;
  const float* xb = x + b * 3 * NP;
  for (int t = tid; t < NP; t += 256){
    sP[t] = make_float4(xb[t], xb[NP + t], xb[2*NP + t], 0.f);
  }
  __syncthreads();
  float4 pc = sP[n];
  unsigned long long bestpk[21];
  #pragma unroll
  for (int o = 0; o < 21; o++) bestpk[o] = 0ull;
  #pragma unroll 1
  for (int ki = 0; ki < KPER; ki++){
    int kg = kc * KPER + ki;
    int j = idxT[kg * (BATCH*NP) + px];
    float4 pj = sP[j];
    float r0 = pj.x - pc.x, r1 = pj.y - pc.y, r2 = pj.z - pc.z;
    float g0 = pj.y*pc.z - pj.z*pc.y, g1 = pj.z*pc.x - pj.x*pc.z, g2 = pj.x*pc.y - pj.y*pc.x;
    float h[21][3];
    #pragma unroll
    for (int o = 0; o < 21; o++){
      float w0 = Wf[o*3], w1 = Wf[o*3+1], w2 = Wf[o*3+2];
      float p0 = w0*r0 + w1*pc.x + w2*g0;
      float p1 = w0*r1 + w1*pc.y + w2*g1;
      float p2 = w0*r2 + w1*pc.z + w2*g2;
      float nm = sqrtf(p0*p0 + p1*p1 + p2*p2) + EPSF;
      float f = (nm - mi[2*o]) * mi[2*o+1] / nm;
      p0 *= f; p1 *= f; p2 *= f;
      float v0 = Wd[o*3], v1 = Wd[o*3+1], v2 = Wd[o*3+2];
      float d0 = v0*r0 + v1*pc.x + v2*g0;
      float d1 = v0*r1 + v1*pc.y + v2*g1;
      float d2 = v0*r2 + v1*pc.z + v2*g2;
      float dot = p0*d0 + p1*d1 + p2*d2;
      float dsq = d0*d0 + d1*d1 + d2*d2;
      float t = dot / (dsq + EPSF);
      h[o][0] = (dot >= 0.f) ? p0 : fmaf(-t, d0, p0);
      h[o][1] = (dot >= 0.f) ? p1 : fmaf(-t, d1, p1);
      h[o][2] = (dot >= 0.f) ? p2 : fmaf(-t, d2, p2);
    }
    #pragma unroll
    for (int o = 0; o < 21; o++){
      float q0 = 0.f, q1 = 0.f, q2 = 0.f;
      #pragma unroll
      for (int c = 0; c < 21; c++){
        float wg = Wg[o*21 + c];
        q0 = fmaf(wg, h[c][0], q0); q1 = fmaf(wg, h[c][1], q1); q2 = fmaf(wg, h[c][2], q2);
      }
      float dp = q0*h[o][0] + q1*h[o][1] + q2*h[o][2];
      unsigned long long pk = ((unsigned long long)ordf(dp) << 32) | (unsigned)(63 - kg);
      if (pk > bestpk[o]) bestpk[o] = pk;
    }
  }
  // combine the 8 k-chunks (lanes differing in low 3 bits)
  #pragma unroll
  for (int o = 0; o < 21; o++){
    unsigned long long v = bestpk[o];
    unsigned long long t = __shfl_xor(v, 1, 64); if (t > v) v = t;
    t = __shfl_xor(v, 2, 64); if (t > v) v = t;
    t = __shfl_xor(v, 4, 64); if (t > v) v = t;
    bestpk[o] = v;
  }
  // recompute winner h per output; lane kc==0 stores
  #pragma unroll
  for (int o = 0; o < 21; o++){
    int kst = 63 - (int)(bestpk[o] & 0xffffffffu);
    int j = idxT[kst * (BATCH*NP) + px];
    float4 pj = sP[j];
    float r0 = pj.x - pc.x, r1 = pj.y - pc.y, r2 = pj.z - pc.z;
    float g0 = pj.y*pc.z - pj.z*pc.y, g1 = pj.z*pc.x - pj.x*pc.z, g2 = pj.x*pc.y - pj.y*pc.x;
    float w0 = Wf[o*3], w1 = Wf[o*3+1], w2 = Wf[o*3+2];
    float p0 = w0*r0 + w1*pc.x + w2*g0;
    float p1 = w0*r1 + w1*pc.y + w2*g1;
    float p2 = w0*r2 + w1*pc.z + w2*g2;
    float nm = sqrtf(p0*p0 + p1*p1 + p2*p2) + EPSF;
    float f = (nm - mi[2*o]) * mi[2*o+1] / nm;
    p0 *= f; p1 *= f; p2 *= f;
    float v0 = Wd[o*3], v1 = Wd[o*3+1], v2 = Wd[o*3+2];
    float d0 = v0*r0 + v1*pc.x + v2*g0;
    float d1 = v0*r1 + v1*pc.y + v2*g1;
    float d2 = v0*r2 + v1*pc.z + v2*g2;
    float dot = p0*d0 + p1*d1 + p2*d2;
    float dsq = d0*d0 + d1*d1 + d2*d2;
    float t = dot / (dsq + EPSF);
    float o0 = (dot >= 0.f) ? p0 : fmaf(-t, d0, p0);
    float o1 = (dot >= 0.f) ? p1 : fmaf(-t, d1, p1);
    float o2 = (dot >= 0.f) ? p2 : fmaf(-t, d2, p2);
    if (kc == 0){
      float* dst = h1 + (size_t)((b*21 + o)*3) * NP + n;
      dst[0] = o0; dst[NP] = o1; dst[2*NP] = o2;
    }
  }
}

// ------- VN layer stats, o-chunked register tiling: block = 1024 px x 8 outputs --------
template<int CIN>
__global__ __launch_bounds__(256) void layer_stats2(const float* __restrict__ hin, const float* __restrict__ Wf,
                                                    double* __restrict__ sums, int Co){
  const int px0 = blockIdx.x * 1024;
  const int b = px0 >> 11;
  const int n0 = (px0 & 2047) + (threadIdx.x << 2);
  const int o0 = blockIdx.y * 8;
  const float* hb = hin + (size_t)b * CIN * 3 * NP + n0;
  float p[8][3][4];
  #pragma unroll
  for (int oo = 0; oo < 8; oo++)
    #pragma unroll
    for (int e = 0; e < 3; e++)
      #pragma unroll
      for (int k = 0; k < 4; k++) p[oo][e][k] = 0.f;
  for (int c = 0; c < CIN; c++){
    float4 hv[3];
    #pragma unroll
    for (int e = 0; e < 3; e++) hv[e] = *(const float4*)&hb[(size_t)(c*3 + e) * NP];
    #pragma unroll
    for (int oo = 0; oo < 8; oo++){
      int o = o0 + oo; if (o >= Co) o = Co - 1;
      float wv = Wf[o*CIN + c];
      #pragma unroll
      for (int e = 0; e < 3; e++){
        p[oo][e][0] = fmaf(wv, hv[e].x, p[oo][e][0]);
        p[oo][e][1] = fmaf(wv, hv[e].y, p[oo][e][1]);
        p[oo][e][2] = fmaf(wv, hv[e].z, p[oo][e][2]);
        p[oo][e][3] = fmaf(wv, hv[e].w, p[oo][e][3]);
      }
    }
  }
  float sl[8], ql[8];
  #pragma unroll
  for (int oo = 0; oo < 8; oo++){
    sl[oo] = 0.f; ql[oo] = 0.f;
    #pragma unroll
    for (int k = 0; k < 4; k++){
      float nm = sqrtf(p[oo][0][k]*p[oo][0][k] + p[oo][1][k]*p[oo][1][k] + p[oo][2][k]*p[oo][2][k]) + EPSF;
      sl[oo] += nm; ql[oo] += nm * nm;
    }
  }
  __shared__ float red[4][16];
  int w = threadIdx.x >> 6;
  #pragma unroll
  for (int oo = 0; oo < 8; oo++){
    float sv = sl[oo], qv = ql[oo];
    #pragma unroll
    for (int st = 1; st < 64; st <<= 1){ sv += __shfl_xor(sv, st, 64); qv += __shfl_xor(qv, st, 64); }
    if ((threadIdx.x & 63) == 0){ red[w][oo] = sv; red[w][8 + oo] = qv; }
  }
  __syncthreads();
  if (threadIdx.x < 16){
    float tot = red[0][threadIdx.x] + red[1][threadIdx.x] + red[2][threadIdx.x] + red[3][threadIdx.x];
    int oo = threadIdx.x & 7, isq = threadIdx.x >> 3;
    int o = o0 + oo;
    if (o < Co) atomicAdd(&sums[2*o + isq], (double)tot);
  }
}

// ------- VN layer apply, o-chunked: block = 256 px x 8 outputs, fp32 out ---------------
template<int CIN>
__global__ __launch_bounds__(256) void layer_apply2(const float* __restrict__ hin, const float* __restrict__ Wf,
    const float* __restrict__ Wd, const float* __restrict__ mi, float* __restrict__ hout, int Co){
  const int px = blockIdx.x * 256 + threadIdx.x;
  const int b = px >> 11, n = px & 2047;
  const int o0 = blockIdx.y * 8;
  const float* hb = hin + (size_t)b * CIN * 3 * NP + n;
  float p[8][3], d[8][3];
  #pragma unroll
  for (int oo = 0; oo < 8; oo++)
    #pragma unroll
    for (int e = 0; e < 3; e++){ p[oo][e] = 0.f; d[oo][e] = 0.f; }
  for (int c = 0; c < CIN; c++){
    float h0 = hb[(size_t)(c*3 + 0) * NP];
    float h1 = hb[(size_t)(c*3 + 1) * NP];
    float h2 = hb[(size_t)(c*3 + 2) * NP];
    #pragma unroll
    for (int oo = 0; oo < 8; oo++){
      int o = o0 + oo; if (o >= Co) o = Co - 1;
      float wf = Wf[o*CIN + c], wd = Wd[o*CIN + c];
      p[oo][0] = fmaf(wf, h0, p[oo][0]); p[oo][1] = fmaf(wf, h1, p[oo][1]); p[oo][2] = fmaf(wf, h2, p[oo][2]);
      d[oo][0] = fmaf(wd, h0, d[oo][0]); d[oo][1] = fmaf(wd, h1, d[oo][1]); d[oo][2] = fmaf(wd, h2, d[oo][2]);
    }
  }
  #pragma unroll
  for (int oo = 0; oo < 8; oo++){
    int o = o0 + oo;
    if (o < Co){
      float nm = sqrtf(p[oo][0]*p[oo][0] + p[oo][1]*p[oo][1] + p[oo][2]*p[oo][2]) + EPSF;
      float f = (nm - mi[2*o]) * mi[2*o+1] / nm;
      float p0 = p[oo][0]*f, p1 = p[oo][1]*f, p2 = p[oo][2]*f;
      float dot = p0*d[oo][0] + p1*d[oo][1] + p2*d[oo][2];
      float dsq = d[oo][0]*d[oo][0] + d[oo][1]*d[oo][1] + d[oo][2]*d[oo][2];
      float t = dot / (dsq + EPSF);
      float r0 = (dot >= 0.f) ? p0 : fmaf(-t, d[oo][0], p0);
      float r1 = (dot >= 0.f) ? p1 : fmaf(-t, d[oo][1], p1);
      float r2 = (dot >= 0.f) ? p2 : fmaf(-t, d[oo][2], p2);
      float* dst = hout + (size_t)((b*Co + o)*3) * NP + n;
      dst[0] = r0; dst[NP] = r1; dst[2*NP] = r2;
    }
  }
}

// ------- last VN layer (42->341): o-chunked apply + k-packed bf16 hi/lo output ---------
__global__ __launch_bounds__(256) void layer_apply_l3v2(const float* __restrict__ hin, const float* __restrict__ Wf,
    const float* __restrict__ Wd, const float* __restrict__ mi,
    unsigned short* __restrict__ Hkh, unsigned short* __restrict__ Hkl){
  const int px = blockIdx.x * 256 + threadIdx.x;
  const int b = px >> 11, n = px & 2047;
  const int o0 = blockIdx.y * 8;
  const float* hb = hin + (size_t)b * 42 * 3 * NP + n;
  float r[8][3];
  #pragma unroll
  for (int oo = 0; oo < 8; oo++)
    #pragma unroll
    for (int e = 0; e < 3; e++) r[oo][e] = 0.f;
  if (o0 < 341){
    float p[8][3], d[8][3];
    #pragma unroll
    for (int oo = 0; oo < 8; oo++)
      #pragma unroll
      for (int e = 0; e < 3; e++){ p[oo][e] = 0.f; d[oo][e] = 0.f; }
    for (int c = 0; c < 42; c++){
      float h0 = hb[(size_t)(c*3 + 0) * NP];
      float h1 = hb[(size_t)(c*3 + 1) * NP];
      float h2 = hb[(size_t)(c*3 + 2) * NP];
      #pragma unroll
      for (int oo = 0; oo < 8; oo++){
        int o = o0 + oo; if (o >= 341) o = 340;
        float wf = Wf[o*42 + c], wd = Wd[o*42 + c];
        p[oo][0] = fmaf(wf, h0, p[oo][0]); p[oo][1] = fmaf(wf, h1, p[oo][1]); p[oo][2] = fmaf(wf, h2, p[oo][2]);
        d[oo][0] = fmaf(wd, h0, d[oo][0]); d[oo][1] = fmaf(wd, h1, d[oo][1]); d[oo][2] = fmaf(wd, h2, d[oo][2]);
      }
    }
    #pragma unroll
    for (int oo = 0; oo < 8; oo++){
      int o = o0 + oo;
      if (o < 341){
        float nm = sqrtf(p[oo][0]*p[oo][0] + p[oo][1]*p[oo][1] + p[oo][2]*p[oo][2]) + EPSF;
        float f = (nm - mi[2*o]) * mi[2*o+1] / nm;
        float p0 = p[oo][0]*f, p1 = p[oo][1]*f, p2 = p[oo][2]*f;
        float dot = p0*d[oo][0] + p1*d[oo][1] + p2*d[oo][2];
        float dsq = d[oo][0]*d[oo][0] + d[oo][1]*d[oo][1] + d[oo][2]*d[oo][2];
        float t = dot / (dsq + EPSF);
        r[oo][0] = (dot >= 0.f) ? p0 : fmaf(-t, d[oo][0], p0);
        r[oo][1] = (dot >= 0.f) ? p1 : fmaf(-t, d[oo][1], p1);
        r[oo][2] = (dot >= 0.f) ? p2 : fmaf(-t, d[oo][2], p2);
      }
    }
  }
  #pragma unroll
  for (int e = 0; e < 3; e++){
    unsigned ph[4], pl[4];
    #pragma unroll
    for (int oo = 0; oo < 8; oo++){
      unsigned short hh, ll;
      bsplit(r[oo][e], hh, ll);
      if (!(oo & 1)){ ph[oo>>1] = hh; pl[oo>>1] = ll; }
      else { ph[oo>>1] |= ((unsigned)hh) << 16; pl[oo>>1] |= ((unsigned)ll) << 16; }
    }
    size_t base = ((((size_t)(b*3 + e))*48 + blockIdx.y) * 2048 + n) * 8;
    *(uint4*)(Hkh + base) = make_uint4(ph[0], ph[1], ph[2], ph[3]);
    *(uint4*)(Hkl + base) = make_uint4(pl[0], pl[1], pl[2], pl[3]);
  }
}

__global__ void finalize_stats(const double* __restrict__ sums, float* __restrict__ mi, int Co, double invM){
  int o = blockIdx.x * 64 + threadIdx.x;
  if (o >= Co) return;
  double m = sums[2*o] * invM;
  double v = sums[2*o+1] * invM - m * m;
  if (v < 0.0) v = 0.0;
  mi[2*o] = (float)m;
  mi[2*o+1] = (float)(1.0 / sqrt(v + (double)BNEPS));
}

// ------- split W_pool into k-packed bf16 hi/lo: Wk[cb=0..43][o=0..383][j=0..7] ---------
__global__ __launch_bounds__(256) void wk_kernel(const float* __restrict__ Wp,
    unsigned short* __restrict__ Wkh, unsigned short* __restrict__ Wkl){
  int t = blockIdx.x * 256 + threadIdx.x;
  if (t >= 44*384*8) return;
  int j = t & 7, o = (t >> 3) % 384, cb = t / (384*8);
  int c = cb*8 + j;
  float v = (c < 341 && o < 341) ? Wp[o*341 + c] : 0.f;
  unsigned short h, l;
  bsplit(v, h, l);
  Wkh[t] = h; Wkl[t] = l;
}

// ------------- pool over N via split-bf16 MFMA: D = Wpool @ H; dot; argmax -------------
__global__ __launch_bounds__(256) void pool_mfma(const unsigned short* __restrict__ Wkh,
    const unsigned short* __restrict__ Wkl, const unsigned short* __restrict__ Hkh,
    const unsigned short* __restrict__ Hkl, unsigned long long* __restrict__ packed){
  __shared__ unsigned short sB[2][2][4][64][8];   // [buf][hi/lo][kb][n][j] = 16 KB
  const int b = blockIdx.z, o0 = blockIdx.y * 128, n0 = blockIdx.x * 64;
  const int t = threadIdx.x, w = t >> 6, l = t & 63;
  const int wo = o0 + w * 32;
  const int r = l & 15, g = l >> 4;
  const int skb = t >> 6, sn = t & 63;
  const int ktw = wo >> 5;

  f32x4 acc[2][4], dotv[2][4], hval[2][4];
  #pragma unroll
  for (int s = 0; s < 2; s++)
    #pragma unroll
    for (int nt = 0; nt < 4; nt++){ dotv[s][nt] = (f32x4)0.f; hval[s][nt] = (f32x4)0.f; }

  auto gsrc = [&](const unsigned short* base, int e, int kt) -> const uint4* {
    return (const uint4*)(base + ((((size_t)(b*3 + e))*48 + (size_t)(kt*4 + skb)) * 2048 + n0 + sn) * 8);
  };

  uint4 rg[2];
  rg[0] = *gsrc(Hkh, 0, 0);
  rg[1] = *gsrc(Hkl, 0, 0);

  for (int ek = 0; ek < 33; ek++){
    const int e = ek / 11, kt = ek - e*11, buf = ek & 1;
    *(uint4*)&sB[buf][0][skb][sn][0] = rg[0];
    *(uint4*)&sB[buf][1][skb][sn][0] = rg[1];
    __syncthreads();
    if (ek < 32){
      int e2 = (ek+1) / 11, kt2 = (ek+1) - e2*11;
      rg[0] = *gsrc(Hkh, e2, kt2);
      rg[1] = *gsrc(Hkl, e2, kt2);
    }
    if (kt == 0){
      #pragma unroll
      for (int s = 0; s < 2; s++)
        #pragma unroll
        for (int nt = 0; nt < 4; nt++) acc[s][nt] = (f32x4)0.f;
    }
    short8 ah[2], al[2];
    #pragma unroll
    for (int s = 0; s < 2; s++){
      size_t aoff = (((size_t)(kt*4 + g)) * 384 + (wo + s*16 + r)) * 8;
      ah[s] = *(const short8*)(Wkh + aoff);
      al[s] = *(const short8*)(Wkl + aoff);
    }
    #pragma unroll
    for (int nt = 0; nt < 4; nt++){
      short8 bh = *(const short8*)&sB[buf][0][g][nt*16 + r][0];
      short8 bl = *(const short8*)&sB[buf][1][g][nt*16 + r][0];
      #pragma unroll
      for (int s = 0; s < 2; s++){
        acc[s][nt] = __builtin_amdgcn_mfma_f32_16x16x32_bf16(ah[s], bh, acc[s][nt], 0, 0, 0);
        acc[s][nt] = __builtin_amdgcn_mfma_f32_16x16x32_bf16(ah[s], bl, acc[s][nt], 0, 0, 0);
        acc[s][nt] = __builtin_amdgcn_mfma_f32_16x16x32_bf16(al[s], bh, acc[s][nt], 0, 0, 0);
      }
    }
    if (kt == ktw){
      #pragma unroll
      for (int s = 0; s < 2; s++){
        #pragma unroll
        for (int jj = 0; jj < 4; jj++){
          int oin = s*16 + g*4 + jj;
          #pragma unroll
          for (int nt = 0; nt < 4; nt++){
            hval[s][nt][jj] = bf2f(sB[buf][0][oin>>3][nt*16 + r][oin&7])
                            + bf2f(sB[buf][1][oin>>3][nt*16 + r][oin&7]);
          }
        }
      }
    }
    __syncthreads();
    if (kt == 10){
      #pragma unroll
      for (int s = 0; s < 2; s++)
        #pragma unroll
        for (int nt = 0; nt < 4; nt++)
          #pragma unroll
          for (int jj = 0; jj < 4; jj++)
            dotv[s][nt][jj] += acc[s][nt][jj] * hval[s][nt][jj];
    }
  }
  #pragma unroll
  for (int s = 0; s < 2; s++){
    #pragma unroll
    for (int j = 0; j < 4; j++){
      int o = wo + s*16 + g*4 + j;
      unsigned long long best = 0;
      #pragma unroll
      for (int nt = 0; nt < 4; nt++){
        int n = n0 + nt*16 + r;
        unsigned long long pk = ((unsigned long long)ordf(dotv[s][nt][j]) << 32) | (unsigned)(2047 - n);
        if (pk > best) best = pk;
      }
      #pragma unroll
      for (int st = 1; st < 16; st <<= 1){
        unsigned long long ob = __shfl_xor(best, st, 64);
        if (ob > best) best = ob;
      }
      if (r == 0 && o < 341) atomicMax(&packed[b*341 + o], best);
    }
  }
}

__global__ void pool_gather(const unsigned long long* __restrict__ packed,
                            const unsigned short* __restrict__ Hkh, const unsigned short* __restrict__ Hkl,
                            float* __restrict__ pooled){
  int t = blockIdx.x * 256 + threadIdx.x;
  if (t >= BATCH * 341) return;
  int n = 2047 - (int)(packed[t] & 0xffffffffu);
  int b = t / 341, o = t % 341;
  #pragma unroll
  for (int e = 0; e < 3; e++){
    size_t hb = ((((size_t)(b*3 + e))*48 + (o >> 3)) * 2048 + n) * 8 + (o & 7);
    pooled[t*3 + e] = bf2f(Hkh[hb]) + bf2f(Hkl[hb]);
  }
}

// -------- fully-connected VN layer (B=8 pixels, per-channel bn over B) -----------------
__global__ __launch_bounds__(64) void flayer(const float* __restrict__ in, const float* __restrict__ Wf,
    const float* __restrict__ Wd, float* __restrict__ out, int Cin, int Co){
  int o = blockIdx.x, lane = threadIdx.x;
  float pv[24], dv[24];
  #pragma unroll
  for (int be = 0; be < 24; be++){ pv[be] = 0.f; dv[be] = 0.f; }
  for (int c = lane; c < Cin; c += 64){
    float wf = Wf[o*Cin + c], wd = Wd[o*Cin + c];
    #pragma unroll
    for (int bb = 0; bb < 8; bb++){
      #pragma unroll
      for (int e = 0; e < 3; e++){
        float hv = in[(bb*Cin + c)*3 + e];
        pv[bb*3+e] = fmaf(wf, hv, pv[bb*3+e]);
        dv[bb*3+e] = fmaf(wd, hv, dv[bb*3+e]);
      }
    }
  }
  #pragma unroll
  for (int be = 0; be < 24; be++){
    #pragma unroll
    for (int st = 1; st < 64; st <<= 1){
      pv[be] += __shfl_xor(pv[be], st, 64);
      dv[be] += __shfl_xor(dv[be], st, 64);
    }
  }
  float nm[8], dotb[8], dsqb[8];
  float mean = 0.f;
  #pragma unroll
  for (int bb = 0; bb < 8; bb++){
    nm[bb] = sqrtf(pv[bb*3]*pv[bb*3] + pv[bb*3+1]*pv[bb*3+1] + pv[bb*3+2]*pv[bb*3+2]) + EPSF;
    mean += nm[bb];
  }
  mean *= 0.125f;
  float var = 0.f;
  #pragma unroll
  for (int bb = 0; bb < 8; bb++){ float dvv = nm[bb] - mean; var += dvv * dvv; }
  var *= 0.125f;
  float istd = 1.f / sqrtf(var + BNEPS);
  #pragma unroll
  for (int bb = 0; bb < 8; bb++){
    float f = (nm[bb] - mean) * istd / nm[bb];
    dotb[bb] = f * (pv[bb*3]*dv[bb*3] + pv[bb*3+1]*dv[bb*3+1] + pv[bb*3+2]*dv[bb*3+2]);
    dsqb[bb] = dv[bb*3]*dv[bb*3] + dv[bb*3+1]*dv[bb*3+1] + dv[bb*3+2]*dv[bb*3+2];
  }
  #pragma unroll
  for (int be = 0; be < 24; be++){
    if (lane == be){
      int bb = be / 3;
      float f = (nm[bb] - mean) * istd / nm[bb];
      float pe = pv[be] * f;
      float t = dotb[bb] / (dsqb[bb] + EPSF);
      float res = (dotb[bb] >= 0.f) ? pe : fmaf(-t, dv[be], pe);
      out[(bb*Co + o)*3 + (be % 3)] = res;
    }
  }
}

__global__ void final_lin(const float* __restrict__ in, const float* __restrict__ W, float* __restrict__ out){
  int t = threadIdx.x;
  if (t >= 72) return;
  int b = t / 9, o = (t % 9) / 3, e = t % 3;
  float s = 0.f;
  for (int c = 0; c < 85; c++) s = fmaf(W[o*85 + c], in[(b*85 + c)*3 + e], s);
  out[t] = s;
}

// --------------------------------- launcher -------------------------------------------
extern "C" void kernel_launch(void* const* d_in, const int* in_sizes, int n_in,
                              void* d_out, int out_size, void* d_ws, size_t ws_size,
                              hipStream_t stream){
  const float* x   = (const float*)d_in[0];
  const float* Wpf = (const float*)d_in[1];
  const float* Wpd = (const float*)d_in[2];
  const float* Wg  = (const float*)d_in[3];
  const float* W1f = (const float*)d_in[4];
  const float* W1d = (const float*)d_in[5];
  const float* W2f = (const float*)d_in[6];
  const float* W2d = (const float*)d_in[7];
  const float* W3f = (const float*)d_in[8];
  const float* W3d = (const float*)d_in[9];
  const float* Wpool = (const float*)d_in[10];
  const float* Wf1f = (const float*)d_in[11];
  const float* Wf1d = (const float*)d_in[12];
  const float* Wf2f = (const float*)d_in[13];
  const float* Wf2d = (const float*)d_in[14];
  const float* Wf3  = (const float*)d_in[15];
  float* out = (float*)d_out;

  char* ws = (char*)d_ws;
  size_t off = 0;
  int*   idx  = (int*)(ws + off);             off += (size_t)BATCH*NP*KNN*4;
  int*   idxT = (int*)(ws + off);             off += (size_t)BATCH*NP*KNN*4;
  float* h1  = (float*)(ws + off);            off += (size_t)BATCH*21*3*NP*4;
  float* h2  = (float*)(ws + off);            off += (size_t)BATCH*21*3*NP*4;
  float* h3  = (float*)(ws + off);            off += (size_t)BATCH*42*3*NP*4;
  unsigned short* Hkh = (unsigned short*)(ws + off); off += (size_t)BATCH*3*48*NP*8*2;
  unsigned short* Hkl = (unsigned short*)(ws + off); off += (size_t)BATCH*3*48*NP*8*2;
  unsigned short* Wkh = (unsigned short*)(ws + off); off += (size_t)44*384*8*2;
  unsigned short* Wkl = (unsigned short*)(ws + off); off += (size_t)44*384*8*2;
  char*  zbase = ws + off;
  double* sums_gf = (double*)(ws + off);      off += 8192;
  double* sums_l1 = (double*)(ws + off);      off += 8192;
  double* sums_l2 = (double*)(ws + off);      off += 8192;
  double* sums_l3 = (double*)(ws + off);      off += 8192;
  unsigned long long* packed = (unsigned long long*)(ws + off); off += 24576;
  size_t zbytes = (ws + off) - zbase;
  float* mi_gf = (float*)(ws + off);          off += 1024;
  float* mi_l1 = (float*)(ws + off);          off += 1024;
  float* mi_l2 = (float*)(ws + off);          off += 1024;
  float* mi_l3 = (float*)(ws + off);          off += 4096;
  float* pooled = (float*)(ws + off);         off += (size_t)BATCH*341*3*4 + 32;
  float* h5 = (float*)(ws + off);             off += (size_t)BATCH*170*3*4 + 32;
  float* h6 = (float*)(ws + off);             off += (size_t)BATCH*85*3*4 + 32;

  hipMemsetAsync(zbase, 0, zbytes, stream);

  knn_kernel<<<BATCH*NP/4, 256, 0, stream>>>(x, idx, idxT);
  wk_kernel<<<(44*384*8 + 255)/256, 256, 0, stream>>>(Wpool, Wkh, Wkl);

  gf_stats<<<256, 256, 0, stream>>>(x, idx, Wpf, sums_gf);
  finalize_stats<<<1, 64, 0, stream>>>(sums_gf, mi_gf, 21, 1.0 / (double)(BATCH*NP*KNN));
  gf_applypool2<<<BATCH*NP/32, 256, 0, stream>>>(x, idxT, Wpf, Wpd, Wg, mi_gf, h1);

  layer_stats2<21><<<dim3(16,3), 256, 0, stream>>>(h1, W1f, sums_l1, 21);
  finalize_stats<<<1, 64, 0, stream>>>(sums_l1, mi_l1, 21, 1.0 / (double)(BATCH*NP));
  layer_apply2<21><<<dim3(64,3), 256, 0, stream>>>(h1, W1f, W1d, mi_l1, h2, 21);

  layer_stats2<21><<<dim3(16,6), 256, 0, stream>>>(h2, W2f, sums_l2, 42);
  finalize_stats<<<1, 64, 0, stream>>>(sums_l2, mi_l2, 42, 1.0 / (double)(BATCH*NP));
  layer_apply2<21><<<dim3(64,6), 256, 0, stream>>>(h2, W2f, W2d, mi_l2, h3, 42);

  layer_stats2<42><<<dim3(16,43), 256, 0, stream>>>(h3, W3f, sums_l3, 341);
  finalize_stats<<<6, 64, 0, stream>>>(sums_l3, mi_l3, 341, 1.0 / (double)(BATCH*NP));
  layer_apply_l3v2<<<dim3(64,44), 256, 0, stream>>>(h3, W3f, W3d, mi_l3, Hkh, Hkl);

  pool_mfma<<<dim3(32, 3, BATCH), 256, 0, stream>>>(Wkh, Wkl, Hkh, Hkl, packed);
  pool_gather<<<(BATCH*341 + 255)/256, 256, 0, stream>>>(packed, Hkh, Hkl, pooled);

  flayer<<<170, 64, 0, stream>>>(pooled, Wf1f, Wf1d, h5, 341, 170);
  flayer<<<85, 64, 0, stream>>>(h5, Wf2f, Wf2d, h6, 170, 85);
  final_lin<<<1, 128, 0, stream>>>(h6, Wf3, out);
}

// Round 8
// 507.265 us; speedup vs baseline: 1.2394x; 1.2394x over previous
//
#include <hip/hip_runtime.h>

#define NP 2048
#define BATCH 8
#define KNN 40
#define EPSF 1e-6f
#define BNEPS 1e-5f

typedef __attribute__((ext_vector_type(8))) short short8;
typedef __attribute__((ext_vector_type(4))) float f32x4;

__device__ __forceinline__ unsigned ordf(float v){
  unsigned u = __float_as_uint(v);
  return (u & 0x80000000u) ? ~u : (u | 0x80000000u);
}

// split fp32 -> bf16 hi (RNE) + bf16 lo (RNE of residual)
__device__ __forceinline__ void bsplit(float v, unsigned short &h, unsigned short &l){
  unsigned u = __float_as_uint(v);
  unsigned hu = (u + 0x7fffu + ((u >> 16) & 1u)) >> 16;
  h = (unsigned short)hu;
  float r = v - __uint_as_float(hu << 16);
  unsigned u2 = __float_as_uint(r);
  l = (unsigned short)((u2 + 0x7fffu + ((u2 >> 16) & 1u)) >> 16);
}

__device__ __forceinline__ float bf2f(unsigned short h){
  return __uint_as_float(((unsigned)h) << 16);
}

// ---------------- KNN: exact top-40 (nearest incl. self), tie -> lowest index ----------
__global__ __launch_bounds__(256) void knn_kernel(const float* __restrict__ x, int* __restrict__ idx){
  __shared__ float4 sP[NP];   // 32 KB
  int tid = threadIdx.x;
  int w = tid >> 6, lane = tid & 63;
  int row = blockIdx.x * 4 + w;
  int b = row >> 11, i = row & 2047;
  const float* xb = x + b * 3 * NP;
  for (int t = tid; t < NP; t += 256){
    float a = xb[t], c = xb[NP + t], d = xb[2*NP + t];
    float xx = __fadd_rn(__fadd_rn(__fmul_rn(a,a), __fmul_rn(c,c)), __fmul_rn(d,d));
    sP[t] = make_float4(a, c, d, xx);
  }
  __syncthreads();
  float4 pi = sP[i];
  const float4* lp = &sP[lane];
  unsigned long long s0 = 0, s1 = 0, s2 = 0, s3 = 0;
  #pragma unroll
  for (int m = 0; m < 32; m++){
    float4 pj = lp[m * 64];
    float dot = __fadd_rn(__fadd_rn(__fmul_rn(pi.x, pj.x), __fmul_rn(pi.y, pj.y)), __fmul_rn(pi.z, pj.z));
    float v = __fsub_rn(__fsub_rn(-pi.w, __fmul_rn(-2.f, dot)), pj.w);
    unsigned long long pk = ((unsigned long long)ordf(v) << 32) | (unsigned)(2047 - (m*64 + lane));
    if (pk > s3){
      if (pk > s2){ s3 = s2; if (pk > s1){ s2 = s1; if (pk > s0){ s1 = s0; s0 = pk; } else s1 = pk; } else s2 = pk; }
      else s3 = pk;
    }
  }
  unsigned myout = 0;
  unsigned long long lastPop = ~0ull;
  for (int kk = 0; kk < KNN; kk++){
    unsigned hv = (unsigned)(s0 >> 32);
    unsigned vm = hv;
    #pragma unroll
    for (int st = 32; st > 0; st >>= 1){
      unsigned o = (unsigned)__shfl_xor((int)vm, st, 64);
      vm = (o > vm) ? o : vm;
    }
    bool cand = (hv == vm);
    unsigned long long msk = __ballot(cand);
    unsigned lo;
    if (__popcll(msk) == 1){
      int wl = __ffsll((unsigned long long)msk) - 1;
      lo = (unsigned)__shfl((int)(unsigned)s0, wl, 64);
    } else {
      unsigned cl = cand ? (unsigned)s0 : 0u;
      #pragma unroll
      for (int st = 32; st > 0; st >>= 1){
        unsigned o = (unsigned)__shfl_xor((int)cl, st, 64);
        cl = (o > cl) ? o : cl;
      }
      lo = cl;
    }
    if (lane == kk) myout = lo;
    if (cand && (unsigned)s0 == lo){
      lastPop = s0;
      s0 = s1; s1 = s2; s2 = s3; s3 = 0;
      if (s0 == 0){
        unsigned long long best = 0;
        #pragma unroll
        for (int m = 0; m < 32; m++){
          float4 pj = lp[m * 64];
          float dot = __fadd_rn(__fadd_rn(__fmul_rn(pi.x, pj.x), __fmul_rn(pi.y, pj.y)), __fmul_rn(pi.z, pj.z));
          float v = __fsub_rn(__fsub_rn(-pi.w, __fmul_rn(-2.f, dot)), pj.w);
          unsigned long long pk = ((unsigned long long)ordf(v) << 32) | (unsigned)(2047 - (m*64 + lane));
          if (pk < lastPop && pk > best) best = pk;
        }
        s0 = best;
      }
    }
  }
  if (lane < KNN) idx[row * KNN + lane] = 2047 - (int)myout;
}

// ------------- graph-feature layer: stats pass (p-norm sums per channel, 21 ch) --------
__global__ __launch_bounds__(256) void gf_stats(const float* __restrict__ x, const int* __restrict__ idx,
                                                const float* __restrict__ Wf, double* __restrict__ sums){
  int tid0 = blockIdx.x * 256 + threadIdx.x;
  float s[21], q[21];
  #pragma unroll
  for (int o = 0; o < 21; o++){ s[o] = 0.f; q[o] = 0.f; }
  for (int pix = tid0; pix < BATCH * NP * KNN; pix += 256 * 256){
    int rem = pix / KNN;
    int n = rem & 2047, b = rem >> 11;
    int j = idx[pix];
    const float* xb = x + b * 3 * NP;
    float c0 = xb[n], c1 = xb[NP + n], c2 = xb[2*NP + n];
    float a0 = xb[j], a1 = xb[NP + j], a2 = xb[2*NP + j];
    float r0 = a0 - c0, r1 = a1 - c1, r2 = a2 - c2;
    float g0 = a1*c2 - a2*c1, g1 = a2*c0 - a0*c2, g2 = a0*c1 - a1*c0;
    #pragma unroll
    for (int o = 0; o < 21; o++){
      float w0 = Wf[o*3], w1 = Wf[o*3+1], w2 = Wf[o*3+2];
      float p0 = w0*r0 + w1*c0 + w2*g0;
      float p1 = w0*r1 + w1*c1 + w2*g1;
      float p2 = w0*r2 + w1*c2 + w2*g2;
      float nm = sqrtf(p0*p0 + p1*p1 + p2*p2) + EPSF;
      s[o] += nm; q[o] += nm * nm;
    }
  }
  __shared__ float bs[4][42];
  int w = threadIdx.x >> 6;
  #pragma unroll
  for (int o = 0; o < 21; o++){
    float a = s[o], bb = q[o];
    #pragma unroll
    for (int st = 1; st < 64; st <<= 1){ a += __shfl_xor(a, st, 64); bb += __shfl_xor(bb, st, 64); }
    if ((threadIdx.x & 63) == 0){ bs[w][o] = a; bs[w][21 + o] = bb; }
  }
  __syncthreads();
  if (threadIdx.x < 42){
    float tot = bs[0][threadIdx.x] + bs[1][threadIdx.x] + bs[2][threadIdx.x] + bs[3][threadIdx.x];
    int o = threadIdx.x % 21, sq = threadIdx.x / 21;
    atomicAdd(&sums[2*o + sq], (double)tot);
  }
}

// -------- graph-feature apply + K-pool: thread = (pixel, k); block = 8 px x 40 k -------
// Per-o packed argmax via LDS ds_max_u64 (no return -> no latency chain); tie -> lowest k.
__global__ __launch_bounds__(320) void gf_applypool3(const float* __restrict__ x, const int* __restrict__ idx,
    const float* __restrict__ Wf, const float* __restrict__ Wd, const float* __restrict__ Wg,
    const float* __restrict__ mi, unsigned long long* __restrict__ packedGF){
  __shared__ unsigned long long sM[8*21];
  const int tid = threadIdx.x;
  for (int t = tid; t < 168; t += 320) sM[t] = 0ull;
  __syncthreads();
  const int pxl = tid / 40, k = tid - pxl * 40;
  const int px = blockIdx.x * 8 + pxl;
  const int b = px >> 11, n = px & 2047;
  const float* xb = x + b * 3 * NP;
  float c0 = xb[n], c1 = xb[NP + n], c2 = xb[2*NP + n];
  int j = idx[(size_t)px * KNN + k];
  float a0 = xb[j], a1 = xb[NP + j], a2 = xb[2*NP + j];
  float r0 = a0 - c0, r1 = a1 - c1, r2 = a2 - c2;
  float g0 = a1*c2 - a2*c1, g1 = a2*c0 - a0*c2, g2 = a0*c1 - a1*c0;
  float h[21][3];
  #pragma unroll
  for (int o = 0; o < 21; o++){
    float w0 = Wf[o*3], w1 = Wf[o*3+1], w2 = Wf[o*3+2];
    float p0 = w0*r0 + w1*c0 + w2*g0;
    float p1 = w0*r1 + w1*c1 + w2*g1;
    float p2 = w0*r2 + w1*c2 + w2*g2;
    float nm = sqrtf(p0*p0 + p1*p1 + p2*p2) + EPSF;
    float f = (nm - mi[2*o]) * mi[2*o+1] / nm;
    p0 *= f; p1 *= f; p2 *= f;
    float v0 = Wd[o*3], v1 = Wd[o*3+1], v2 = Wd[o*3+2];
    float d0 = v0*r0 + v1*c0 + v2*g0;
    float d1 = v0*r1 + v1*c1 + v2*g1;
    float d2 = v0*r2 + v1*c2 + v2*g2;
    float dot = p0*d0 + p1*d1 + p2*d2;
    float dsq = d0*d0 + d1*d1 + d2*d2;
    float t = dot / (dsq + EPSF);
    h[o][0] = (dot >= 0.f) ? p0 : fmaf(-t, d0, p0);
    h[o][1] = (dot >= 0.f) ? p1 : fmaf(-t, d1, p1);
    h[o][2] = (dot >= 0.f) ? p2 : fmaf(-t, d2, p2);
  }
  #pragma unroll
  for (int o = 0; o < 21; o++){
    float q0 = 0.f, q1 = 0.f, q2 = 0.f;
    #pragma unroll
    for (int c = 0; c < 21; c++){
      float wg = Wg[o*21 + c];
      q0 = fmaf(wg, h[c][0], q0); q1 = fmaf(wg, h[c][1], q1); q2 = fmaf(wg, h[c][2], q2);
    }
    float dp = q0*h[o][0] + q1*h[o][1] + q2*h[o][2];
    unsigned long long pk = ((unsigned long long)ordf(dp) << 32) | (unsigned)(63 - k);
    atomicMax(&sM[pxl*21 + o], pk);
  }
  __syncthreads();
  for (int t = tid; t < 168; t += 320){
    int lpx = t / 21, lo = t - lpx * 21;
    packedGF[(size_t)(blockIdx.x * 8 + lpx) * 21 + lo] = sM[t];
  }
}

// -------- gather winners: recompute h_o for the winning k, store h1 --------------------
__global__ __launch_bounds__(256) void gf_gather(const float* __restrict__ x, const int* __restrict__ idx,
    const float* __restrict__ Wf, const float* __restrict__ Wd, const float* __restrict__ mi,
    const unsigned long long* __restrict__ packedGF, float* __restrict__ h1){
  int t = blockIdx.x * 256 + threadIdx.x;
  if (t >= BATCH * NP * 21) return;
  int px = t / 21, o = t - px * 21;
  int b = px >> 11, n = px & 2047;
  int k = 63 - (int)(packedGF[t] & 0xffffffffu);
  int j = idx[(size_t)px * KNN + k];
  const float* xb = x + b * 3 * NP;
  float c0 = xb[n], c1 = xb[NP + n], c2 = xb[2*NP + n];
  float a0 = xb[j], a1 = xb[NP + j], a2 = xb[2*NP + j];
  float r0 = a0 - c0, r1 = a1 - c1, r2 = a2 - c2;
  float g0 = a1*c2 - a2*c1, g1 = a2*c0 - a0*c2, g2 = a0*c1 - a1*c0;
  float w0 = Wf[o*3], w1 = Wf[o*3+1], w2 = Wf[o*3+2];
  float p0 = w0*r0 + w1*c0 + w2*g0;
  float p1 = w0*r1 + w1*c1 + w2*g1;
  float p2 = w0*r2 + w1*c2 + w2*g2;
  float nm = sqrtf(p0*p0 + p1*p1 + p2*p2) + EPSF;
  float f = (nm - mi[2*o]) * mi[2*o+1] / nm;
  p0 *= f; p1 *= f; p2 *= f;
  float v0 = Wd[o*3], v1 = Wd[o*3+1], v2 = Wd[o*3+2];
  float d0 = v0*r0 + v1*c0 + v2*g0;
  float d1 = v0*r1 + v1*c1 + v2*g1;
  float d2 = v0*r2 + v1*c2 + v2*g2;
  float dot = p0*d0 + p1*d1 + p2*d2;
  float dsq = d0*d0 + d1*d1 + d2*d2;
  float tt = dot / (dsq + EPSF);
  float o0 = (dot >= 0.f) ? p0 : fmaf(-tt, d0, p0);
  float o1 = (dot >= 0.f) ? p1 : fmaf(-tt, d1, p1);
  float o2 = (dot >= 0.f) ? p2 : fmaf(-tt, d2, p2);
  float* dst = h1 + (size_t)((b*21 + o)*3) * NP + n;
  dst[0] = o0; dst[NP] = o1; dst[2*NP] = o2;
}

// ------- VN layer stats, o-chunked register tiling: block = 1024 px x 8 outputs --------
template<int CIN>
__global__ __launch_bounds__(256) void layer_stats2(const float* __restrict__ hin, const float* __restrict__ Wf,
                                                    double* __restrict__ sums, int Co){
  const int px0 = blockIdx.x * 1024;
  const int b = px0 >> 11;
  const int n0 = (px0 & 2047) + (threadIdx.x << 2);
  const int o0 = blockIdx.y * 8;
  const float* hb = hin + (size_t)b * CIN * 3 * NP + n0;
  float p[8][3][4];
  #pragma unroll
  for (int oo = 0; oo < 8; oo++)
    #pragma unroll
    for (int e = 0; e < 3; e++)
      #pragma unroll
      for (int k = 0; k < 4; k++) p[oo][e][k] = 0.f;
  for (int c = 0; c < CIN; c++){
    float4 hv[3];
    #pragma unroll
    for (int e = 0; e < 3; e++) hv[e] = *(const float4*)&hb[(size_t)(c*3 + e) * NP];
    #pragma unroll
    for (int oo = 0; oo < 8; oo++){
      int o = o0 + oo; if (o >= Co) o = Co - 1;
      float wv = Wf[o*CIN + c];
      #pragma unroll
      for (int e = 0; e < 3; e++){
        p[oo][e][0] = fmaf(wv, hv[e].x, p[oo][e][0]);
        p[oo][e][1] = fmaf(wv, hv[e].y, p[oo][e][1]);
        p[oo][e][2] = fmaf(wv, hv[e].z, p[oo][e][2]);
        p[oo][e][3] = fmaf(wv, hv[e].w, p[oo][e][3]);
      }
    }
  }
  float sl[8], ql[8];
  #pragma unroll
  for (int oo = 0; oo < 8; oo++){
    sl[oo] = 0.f; ql[oo] = 0.f;
    #pragma unroll
    for (int k = 0; k < 4; k++){
      float nm = sqrtf(p[oo][0][k]*p[oo][0][k] + p[oo][1][k]*p[oo][1][k] + p[oo][2][k]*p[oo][2][k]) + EPSF;
      sl[oo] += nm; ql[oo] += nm * nm;
    }
  }
  __shared__ float red[4][16];
  int w = threadIdx.x >> 6;
  #pragma unroll
  for (int oo = 0; oo < 8; oo++){
    float sv = sl[oo], qv = ql[oo];
    #pragma unroll
    for (int st = 1; st < 64; st <<= 1){ sv += __shfl_xor(sv, st, 64); qv += __shfl_xor(qv, st, 64); }
    if ((threadIdx.x & 63) == 0){ red[w][oo] = sv; red[w][8 + oo] = qv; }
  }
  __syncthreads();
  if (threadIdx.x < 16){
    float tot = red[0][threadIdx.x] + red[1][threadIdx.x] + red[2][threadIdx.x] + red[3][threadIdx.x];
    int oo = threadIdx.x & 7, isq = threadIdx.x >> 3;
    int o = o0 + oo;
    if (o < Co) atomicAdd(&sums[2*o + isq], (double)tot);
  }
}

// ------- VN layer apply, o-chunked: block = 256 px x 8 outputs, fp32 out ---------------
template<int CIN>
__global__ __launch_bounds__(256) void layer_apply2(const float* __restrict__ hin, const float* __restrict__ Wf,
    const float* __restrict__ Wd, const float* __restrict__ mi, float* __restrict__ hout, int Co){
  const int px = blockIdx.x * 256 + threadIdx.x;
  const int b = px >> 11, n = px & 2047;
  const int o0 = blockIdx.y * 8;
  const float* hb = hin + (size_t)b * CIN * 3 * NP + n;
  float p[8][3], d[8][3];
  #pragma unroll
  for (int oo = 0; oo < 8; oo++)
    #pragma unroll
    for (int e = 0; e < 3; e++){ p[oo][e] = 0.f; d[oo][e] = 0.f; }
  for (int c = 0; c < CIN; c++){
    float h0 = hb[(size_t)(c*3 + 0) * NP];
    float h1 = hb[(size_t)(c*3 + 1) * NP];
    float h2 = hb[(size_t)(c*3 + 2) * NP];
    #pragma unroll
    for (int oo = 0; oo < 8; oo++){
      int o = o0 + oo; if (o >= Co) o = Co - 1;
      float wf = Wf[o*CIN + c], wd = Wd[o*CIN + c];
      p[oo][0] = fmaf(wf, h0, p[oo][0]); p[oo][1] = fmaf(wf, h1, p[oo][1]); p[oo][2] = fmaf(wf, h2, p[oo][2]);
      d[oo][0] = fmaf(wd, h0, d[oo][0]); d[oo][1] = fmaf(wd, h1, d[oo][1]); d[oo][2] = fmaf(wd, h2, d[oo][2]);
    }
  }
  #pragma unroll
  for (int oo = 0; oo < 8; oo++){
    int o = o0 + oo;
    if (o < Co){
      float nm = sqrtf(p[oo][0]*p[oo][0] + p[oo][1]*p[oo][1] + p[oo][2]*p[oo][2]) + EPSF;
      float f = (nm - mi[2*o]) * mi[2*o+1] / nm;
      float p0 = p[oo][0]*f, p1 = p[oo][1]*f, p2 = p[oo][2]*f;
      float dot = p0*d[oo][0] + p1*d[oo][1] + p2*d[oo][2];
      float dsq = d[oo][0]*d[oo][0] + d[oo][1]*d[oo][1] + d[oo][2]*d[oo][2];
      float t = dot / (dsq + EPSF);
      float r0 = (dot >= 0.f) ? p0 : fmaf(-t, d[oo][0], p0);
      float r1 = (dot >= 0.f) ? p1 : fmaf(-t, d[oo][1], p1);
      float r2 = (dot >= 0.f) ? p2 : fmaf(-t, d[oo][2], p2);
      float* dst = hout + (size_t)((b*Co + o)*3) * NP + n;
      dst[0] = r0; dst[NP] = r1; dst[2*NP] = r2;
    }
  }
}

// ------- last VN layer (42->341): o-chunked apply + k-packed bf16 hi/lo output ---------
__global__ __launch_bounds__(256) void layer_apply_l3v2(const float* __restrict__ hin, const float* __restrict__ Wf,
    const float* __restrict__ Wd, const float* __restrict__ mi,
    unsigned short* __restrict__ Hkh, unsigned short* __restrict__ Hkl){
  const int px = blockIdx.x * 256 + threadIdx.x;
  const int b = px >> 11, n = px & 2047;
  const int o0 = blockIdx.y * 8;
  const float* hb = hin + (size_t)b * 42 * 3 * NP + n;
  float r[8][3];
  #pragma unroll
  for (int oo = 0; oo < 8; oo++)
    #pragma unroll
    for (int e = 0; e < 3; e++) r[oo][e] = 0.f;
  if (o0 < 341){
    float p[8][3], d[8][3];
    #pragma unroll
    for (int oo = 0; oo < 8; oo++)
      #pragma unroll
      for (int e = 0; e < 3; e++){ p[oo][e] = 0.f; d[oo][e] = 0.f; }
    for (int c = 0; c < 42; c++){
      float h0 = hb[(size_t)(c*3 + 0) * NP];
      float h1 = hb[(size_t)(c*3 + 1) * NP];
      float h2 = hb[(size_t)(c*3 + 2) * NP];
      #pragma unroll
      for (int oo = 0; oo < 8; oo++){
        int o = o0 + oo; if (o >= 341) o = 340;
        float wf = Wf[o*42 + c], wd = Wd[o*42 + c];
        p[oo][0] = fmaf(wf, h0, p[oo][0]); p[oo][1] = fmaf(wf, h1, p[oo][1]); p[oo][2] = fmaf(wf, h2, p[oo][2]);
        d[oo][0] = fmaf(wd, h0, d[oo][0]); d[oo][1] = fmaf(wd, h1, d[oo][1]); d[oo][2] = fmaf(wd, h2, d[oo][2]);
      }
    }
    #pragma unroll
    for (int oo = 0; oo < 8; oo++){
      int o = o0 + oo;
      if (o < 341){
        float nm = sqrtf(p[oo][0]*p[oo][0] + p[oo][1]*p[oo][1] + p[oo][2]*p[oo][2]) + EPSF;
        float f = (nm - mi[2*o]) * mi[2*o+1] / nm;
        float p0 = p[oo][0]*f, p1 = p[oo][1]*f, p2 = p[oo][2]*f;
        float dot = p0*d[oo][0] + p1*d[oo][1] + p2*d[oo][2];
        float dsq = d[oo][0]*d[oo][0] + d[oo][1]*d[oo][1] + d[oo][2]*d[oo][2];
        float t = dot / (dsq + EPSF);
        r[oo][0] = (dot >= 0.f) ? p0 : fmaf(-t, d[oo][0], p0);
        r[oo][1] = (dot >= 0.f) ? p1 : fmaf(-t, d[oo][1], p1);
        r[oo][2] = (dot >= 0.f) ? p2 : fmaf(-t, d[oo][2], p2);
      }
    }
  }
  #pragma unroll
  for (int e = 0; e < 3; e++){
    unsigned ph[4], pl[4];
    #pragma unroll
    for (int oo = 0; oo < 8; oo++){
      unsigned short hh, ll;
      bsplit(r[oo][e], hh, ll);
      if (!(oo & 1)){ ph[oo>>1] = hh; pl[oo>>1] = ll; }
      else { ph[oo>>1] |= ((unsigned)hh) << 16; pl[oo>>1] |= ((unsigned)ll) << 16; }
    }
    size_t base = ((((size_t)(b*3 + e))*48 + blockIdx.y) * 2048 + n) * 8;
    *(uint4*)(Hkh + base) = make_uint4(ph[0], ph[1], ph[2], ph[3]);
    *(uint4*)(Hkl + base) = make_uint4(pl[0], pl[1], pl[2], pl[3]);
  }
}

__global__ void finalize_stats(const double* __restrict__ sums, float* __restrict__ mi, int Co, double invM){
  int o = blockIdx.x * 64 + threadIdx.x;
  if (o >= Co) return;
  double m = sums[2*o] * invM;
  double v = sums[2*o+1] * invM - m * m;
  if (v < 0.0) v = 0.0;
  mi[2*o] = (float)m;
  mi[2*o+1] = (float)(1.0 / sqrt(v + (double)BNEPS));
}

// ------- split W_pool into k-packed bf16 hi/lo: Wk[cb=0..43][o=0..383][j=0..7] ---------
__global__ __launch_bounds__(256) void wk_kernel(const float* __restrict__ Wp,
    unsigned short* __restrict__ Wkh, unsigned short* __restrict__ Wkl){
  int t = blockIdx.x * 256 + threadIdx.x;
  if (t >= 44*384*8) return;
  int j = t & 7, o = (t >> 3) % 384, cb = t / (384*8);
  int c = cb*8 + j;
  float v = (c < 341 && o < 341) ? Wp[o*341 + c] : 0.f;
  unsigned short h, l;
  bsplit(v, h, l);
  Wkh[t] = h; Wkl[t] = l;
}

// ------------- pool over N via split-bf16 MFMA: D = Wpool @ H; dot; argmax -------------
__global__ __launch_bounds__(256) void pool_mfma(const unsigned short* __restrict__ Wkh,
    const unsigned short* __restrict__ Wkl, const unsigned short* __restrict__ Hkh,
    const unsigned short* __restrict__ Hkl, unsigned long long* __restrict__ packed){
  __shared__ unsigned short sB[2][2][4][64][8];   // [buf][hi/lo][kb][n][j] = 16 KB
  const int b = blockIdx.z, o0 = blockIdx.y * 128, n0 = blockIdx.x * 64;
  const int t = threadIdx.x, w = t >> 6, l = t & 63;
  const int wo = o0 + w * 32;
  const int r = l & 15, g = l >> 4;
  const int skb = t >> 6, sn = t & 63;
  const int ktw = wo >> 5;

  f32x4 acc[2][4], dotv[2][4], hval[2][4];
  #pragma unroll
  for (int s = 0; s < 2; s++)
    #pragma unroll
    for (int nt = 0; nt < 4; nt++){ dotv[s][nt] = (f32x4)0.f; hval[s][nt] = (f32x4)0.f; }

  auto gsrc = [&](const unsigned short* base, int e, int kt) -> const uint4* {
    return (const uint4*)(base + ((((size_t)(b*3 + e))*48 + (size_t)(kt*4 + skb)) * 2048 + n0 + sn) * 8);
  };

  uint4 rg[2];
  rg[0] = *gsrc(Hkh, 0, 0);
  rg[1] = *gsrc(Hkl, 0, 0);

  for (int ek = 0; ek < 33; ek++){
    const int e = ek / 11, kt = ek - e*11, buf = ek & 1;
    *(uint4*)&sB[buf][0][skb][sn][0] = rg[0];
    *(uint4*)&sB[buf][1][skb][sn][0] = rg[1];
    __syncthreads();
    if (ek < 32){
      int e2 = (ek+1) / 11, kt2 = (ek+1) - e2*11;
      rg[0] = *gsrc(Hkh, e2, kt2);
      rg[1] = *gsrc(Hkl, e2, kt2);
    }
    if (kt == 0){
      #pragma unroll
      for (int s = 0; s < 2; s++)
        #pragma unroll
        for (int nt = 0; nt < 4; nt++) acc[s][nt] = (f32x4)0.f;
    }
    short8 ah[2], al[2];
    #pragma unroll
    for (int s = 0; s < 2; s++){
      size_t aoff = (((size_t)(kt*4 + g)) * 384 + (wo + s*16 + r)) * 8;
      ah[s] = *(const short8*)(Wkh + aoff);
      al[s] = *(const short8*)(Wkl + aoff);
    }
    #pragma unroll
    for (int nt = 0; nt < 4; nt++){
      short8 bh = *(const short8*)&sB[buf][0][g][nt*16 + r][0];
      short8 bl = *(const short8*)&sB[buf][1][g][nt*16 + r][0];
      #pragma unroll
      for (int s = 0; s < 2; s++){
        acc[s][nt] = __builtin_amdgcn_mfma_f32_16x16x32_bf16(ah[s], bh, acc[s][nt], 0, 0, 0);
        acc[s][nt] = __builtin_amdgcn_mfma_f32_16x16x32_bf16(ah[s], bl, acc[s][nt], 0, 0, 0);
        acc[s][nt] = __builtin_amdgcn_mfma_f32_16x16x32_bf16(al[s], bh, acc[s][nt], 0, 0, 0);
      }
    }
    if (kt == ktw){
      #pragma unroll
      for (int s = 0; s < 2; s++){
        #pragma unroll
        for (int jj = 0; jj < 4; jj++){
          int oin = s*16 + g*4 + jj;
          #pragma unroll
          for (int nt = 0; nt < 4; nt++){
            hval[s][nt][jj] = bf2f(sB[buf][0][oin>>3][nt*16 + r][oin&7])
                            + bf2f(sB[buf][1][oin>>3][nt*16 + r][oin&7]);
          }
        }
      }
    }
    __syncthreads();
    if (kt == 10){
      #pragma unroll
      for (int s = 0; s < 2; s++)
        #pragma unroll
        for (int nt = 0; nt < 4; nt++)
          #pragma unroll
          for (int jj = 0; jj < 4; jj++)
            dotv[s][nt][jj] += acc[s][nt][jj] * hval[s][nt][jj];
    }
  }
  #pragma unroll
  for (int s = 0; s < 2; s++){
    #pragma unroll
    for (int j = 0; j < 4; j++){
      int o = wo + s*16 + g*4 + j;
      unsigned long long best = 0;
      #pragma unroll
      for (int nt = 0; nt < 4; nt++){
        int n = n0 + nt*16 + r;
        unsigned long long pk = ((unsigned long long)ordf(dotv[s][nt][j]) << 32) | (unsigned)(2047 - n);
        if (pk > best) best = pk;
      }
      #pragma unroll
      for (int st = 1; st < 16; st <<= 1){
        unsigned long long ob = __shfl_xor(best, st, 64);
        if (ob > best) best = ob;
      }
      if (r == 0 && o < 341) atomicMax(&packed[b*341 + o], best);
    }
  }
}

__global__ void pool_gather(const unsigned long long* __restrict__ packed,
                            const unsigned short* __restrict__ Hkh, const unsigned short* __restrict__ Hkl,
                            float* __restrict__ pooled){
  int t = blockIdx.x * 256 + threadIdx.x;
  if (t >= BATCH * 341) return;
  int n = 2047 - (int)(packed[t] & 0xffffffffu);
  int b = t / 341, o = t % 341;
  #pragma unroll
  for (int e = 0; e < 3; e++){
    size_t hb = ((((size_t)(b*3 + e))*48 + (o >> 3)) * 2048 + n) * 8 + (o & 7);
    pooled[t*3 + e] = bf2f(Hkh[hb]) + bf2f(Hkl[hb]);
  }
}

// -------- fully-connected VN layer (B=8 pixels, per-channel bn over B) -----------------
__global__ __launch_bounds__(64) void flayer(const float* __restrict__ in, const float* __restrict__ Wf,
    const float* __restrict__ Wd, float* __restrict__ out, int Cin, int Co){
  int o = blockIdx.x, lane = threadIdx.x;
  float pv[24], dv[24];
  #pragma unroll
  for (int be = 0; be < 24; be++){ pv[be] = 0.f; dv[be] = 0.f; }
  for (int c = lane; c < Cin; c += 64){
    float wf = Wf[o*Cin + c], wd = Wd[o*Cin + c];
    #pragma unroll
    for (int bb = 0; bb < 8; bb++){
      #pragma unroll
      for (int e = 0; e < 3; e++){
        float hv = in[(bb*Cin + c)*3 + e];
        pv[bb*3+e] = fmaf(wf, hv, pv[bb*3+e]);
        dv[bb*3+e] = fmaf(wd, hv, dv[bb*3+e]);
      }
    }
  }
  #pragma unroll
  for (int be = 0; be < 24; be++){
    #pragma unroll
    for (int st = 1; st < 64; st <<= 1){
      pv[be] += __shfl_xor(pv[be], st, 64);
      dv[be] += __shfl_xor(dv[be], st, 64);
    }
  }
  float nm[8], dotb[8], dsqb[8];
  float mean = 0.f;
  #pragma unroll
  for (int bb = 0; bb < 8; bb++){
    nm[bb] = sqrtf(pv[bb*3]*pv[bb*3] + pv[bb*3+1]*pv[bb*3+1] + pv[bb*3+2]*pv[bb*3+2]) + EPSF;
    mean += nm[bb];
  }
  mean *= 0.125f;
  float var = 0.f;
  #pragma unroll
  for (int bb = 0; bb < 8; bb++){ float dvv = nm[bb] - mean; var += dvv * dvv; }
  var *= 0.125f;
  float istd = 1.f / sqrtf(var + BNEPS);
  #pragma unroll
  for (int bb = 0; bb < 8; bb++){
    float f = (nm[bb] - mean) * istd / nm[bb];
    dotb[bb] = f * (pv[bb*3]*dv[bb*3] + pv[bb*3+1]*dv[bb*3+1] + pv[bb*3+2]*dv[bb*3+2]);
    dsqb[bb] = dv[bb*3]*dv[bb*3] + dv[bb*3+1]*dv[bb*3+1] + dv[bb*3+2]*dv[bb*3+2];
  }
  #pragma unroll
  for (int be = 0; be < 24; be++){
    if (lane == be){
      int bb = be / 3;
      float f = (nm[bb] - mean) * istd / nm[bb];
      float pe = pv[be] * f;
      float t = dotb[bb] / (dsqb[bb] + EPSF);
      float res = (dotb[bb] >= 0.f) ? pe : fmaf(-t, dv[be], pe);
      out[(bb*Co + o)*3 + (be % 3)] = res;
    }
  }
}

__global__ void final_lin(const float* __restrict__ in, const float* __restrict__ W, float* __restrict__ out){
  int t = threadIdx.x;
  if (t >= 72) return;
  int b = t / 9, o = (t % 9) / 3, e = t % 3;
  float s = 0.f;
  for (int c = 0; c < 85; c++) s = fmaf(W[o*85 + c], in[(b*85 + c)*3 + e], s);
  out[t] = s;
}

// --------------------------------- launcher -------------------------------------------
extern "C" void kernel_launch(void* const* d_in, const int* in_sizes, int n_in,
                              void* d_out, int out_size, void* d_ws, size_t ws_size,
                              hipStream_t stream){
  const float* x   = (const float*)d_in[0];
  const float* Wpf = (const float*)d_in[1];
  const float* Wpd = (const float*)d_in[2];
  const float* Wg  = (const float*)d_in[3];
  const float* W1f = (const float*)d_in[4];
  const float* W1d = (const float*)d_in[5];
  const float* W2f = (const float*)d_in[6];
  const float* W2d = (const float*)d_in[7];
  const float* W3f = (const float*)d_in[8];
  const float* W3d = (const float*)d_in[9];
  const float* Wpool = (const float*)d_in[10];
  const float* Wf1f = (const float*)d_in[11];
  const float* Wf1d = (const float*)d_in[12];
  const float* Wf2f = (const float*)d_in[13];
  const float* Wf2d = (const float*)d_in[14];
  const float* Wf3  = (const float*)d_in[15];
  float* out = (float*)d_out;

  char* ws = (char*)d_ws;
  size_t off = 0;
  int*   idx  = (int*)(ws + off);             off += (size_t)BATCH*NP*KNN*4;
  unsigned long long* packedGF = (unsigned long long*)(ws + off); off += (size_t)BATCH*NP*21*8;
  float* h1  = (float*)(ws + off);            off += (size_t)BATCH*21*3*NP*4;
  float* h2  = (float*)(ws + off);            off += (size_t)BATCH*21*3*NP*4;
  float* h3  = (float*)(ws + off);            off += (size_t)BATCH*42*3*NP*4;
  unsigned short* Hkh = (unsigned short*)(ws + off); off += (size_t)BATCH*3*48*NP*8*2;
  unsigned short* Hkl = (unsigned short*)(ws + off); off += (size_t)BATCH*3*48*NP*8*2;
  unsigned short* Wkh = (unsigned short*)(ws + off); off += (size_t)44*384*8*2;
  unsigned short* Wkl = (unsigned short*)(ws + off); off += (size_t)44*384*8*2;
  char*  zbase = ws + off;
  double* sums_gf = (double*)(ws + off);      off += 8192;
  double* sums_l1 = (double*)(ws + off);      off += 8192;
  double* sums_l2 = (double*)(ws + off);      off += 8192;
  double* sums_l3 = (double*)(ws + off);      off += 8192;
  unsigned long long* packed = (unsigned long long*)(ws + off); off += 24576;
  size_t zbytes = (ws + off) - zbase;
  float* mi_gf = (float*)(ws + off);          off += 1024;
  float* mi_l1 = (float*)(ws + off);          off += 1024;
  float* mi_l2 = (float*)(ws + off);          off += 1024;
  float* mi_l3 = (float*)(ws + off);          off += 4096;
  float* pooled = (float*)(ws + off);         off += (size_t)BATCH*341*3*4 + 32;
  float* h5 = (float*)(ws + off);             off += (size_t)BATCH*170*3*4 + 32;
  float* h6 = (float*)(ws + off);             off += (size_t)BATCH*85*3*4 + 32;

  hipMemsetAsync(zbase, 0, zbytes, stream);

  knn_kernel<<<BATCH*NP/4, 256, 0, stream>>>(x, idx);
  wk_kernel<<<(44*384*8 + 255)/256, 256, 0, stream>>>(Wpool, Wkh, Wkl);

  gf_stats<<<256, 256, 0, stream>>>(x, idx, Wpf, sums_gf);
  finalize_stats<<<1, 64, 0, stream>>>(sums_gf, mi_gf, 21, 1.0 / (double)(BATCH*NP*KNN));
  gf_applypool3<<<BATCH*NP/8, 320, 0, stream>>>(x, idx, Wpf, Wpd, Wg, mi_gf, packedGF);
  gf_gather<<<(BATCH*NP*21 + 255)/256, 256, 0, stream>>>(x, idx, Wpf, Wpd, mi_gf, packedGF, h1);

  layer_stats2<21><<<dim3(16,3), 256, 0, stream>>>(h1, W1f, sums_l1, 21);
  finalize_stats<<<1, 64, 0, stream>>>(sums_l1, mi_l1, 21, 1.0 / (double)(BATCH*NP));
  layer_apply2<21><<<dim3(64,3), 256, 0, stream>>>(h1, W1f, W1d, mi_l1, h2, 21);

  layer_stats2<21><<<dim3(16,6), 256, 0, stream>>>(h2, W2f, sums_l2, 42);
  finalize_stats<<<1, 64, 0, stream>>>(sums_l2, mi_l2, 42, 1.0 / (double)(BATCH*NP));
  layer_apply2<21><<<dim3(64,6), 256, 0, stream>>>(h2, W2f, W2d, mi_l2, h3, 42);

  layer_stats2<42><<<dim3(16,43), 256, 0, stream>>>(h3, W3f, sums_l3, 341);
  finalize_stats<<<6, 64, 0, stream>>>(sums_l3, mi_l3, 341, 1.0 / (double)(BATCH*NP));
  layer_apply_l3v2<<<dim3(64,44), 256, 0, stream>>>(h3, W3f, W3d, mi_l3, Hkh, Hkl);

  pool_mfma<<<dim3(32, 3, BATCH), 256, 0, stream>>>(Wkh, Wkl, Hkh, Hkl, packed);
  pool_gather<<<(BATCH*341 + 255)/256, 256, 0, stream>>>(packed, Hkh, Hkl, pooled);

  flayer<<<170, 64, 0, stream>>>(pooled, Wf1f, Wf1d, h5, 341, 170);
  flayer<<<85, 64, 0, stream>>>(h5, Wf2f, Wf2d, h6, 170, 85);
  final_lin<<<1, 128, 0, stream>>>(h6, Wf3, out);
}

// Round 11
// 490.885 us; speedup vs baseline: 1.2807x; 1.0334x over previous
//
#include <hip/hip_runtime.h>

#define NP 2048
#define BATCH 8
#define KNN 40
#define EPSF 1e-6f
#define BNEPS 1e-5f

typedef __attribute__((ext_vector_type(8))) short short8;
typedef __attribute__((ext_vector_type(4))) float f32x4;

__device__ __forceinline__ unsigned ordf(float v){
  unsigned u = __float_as_uint(v);
  return (u & 0x80000000u) ? ~u : (u | 0x80000000u);
}

// split fp32 -> bf16 hi (RNE) + bf16 lo (RNE of residual)
__device__ __forceinline__ void bsplit(float v, unsigned short &h, unsigned short &l){
  unsigned u = __float_as_uint(v);
  unsigned hu = (u + 0x7fffu + ((u >> 16) & 1u)) >> 16;
  h = (unsigned short)hu;
  float r = v - __uint_as_float(hu << 16);
  unsigned u2 = __float_as_uint(r);
  l = (unsigned short)((u2 + 0x7fffu + ((u2 >> 16) & 1u)) >> 16);
}

__device__ __forceinline__ float bf2f(unsigned short h){
  return __uint_as_float(((unsigned)h) << 16);
}

// ---------------- KNN: exact top-40 (nearest incl. self), tie -> lowest index ----------
// R8 exact pop-loop algorithm (known-good), restructured for ILP: each wave owns TWO
// rows; the two serial shuffle-reduce pop chains are interleaved stage-by-stage so the
// cross-lane latency of one hides the other. 8 rows/block share one LDS stage of sP.
// (R9/R10 bitonic-sort experiment reverted: 2 rounds, identical unexplained miscompares.)
__global__ __launch_bounds__(256) void knn_kernel(const float* __restrict__ x, int* __restrict__ idx){
  __shared__ float4 sP[NP];   // 32 KB
  int tid = threadIdx.x;
  int w = tid >> 6, lane = tid & 63;
  int row0 = blockIdx.x * 8 + w * 2, row1 = row0 + 1;
  int b = row0 >> 11;
  int i0 = row0 & 2047, i1 = row1 & 2047;
  const float* xb = x + b * 3 * NP;
  for (int t = tid; t < NP; t += 256){
    float a = xb[t], c = xb[NP + t], d = xb[2*NP + t];
    float xx = __fadd_rn(__fadd_rn(__fmul_rn(a,a), __fmul_rn(c,c)), __fmul_rn(d,d));
    sP[t] = make_float4(a, c, d, xx);
  }
  __syncthreads();
  float4 pa = sP[i0];
  float4 pb = sP[i1];
  const float4* lp = &sP[lane];
  unsigned long long a0 = 0, a1 = 0, a2 = 0, a3 = 0;
  unsigned long long b0 = 0, b1 = 0, b2 = 0, b3 = 0;
  #pragma unroll
  for (int m = 0; m < 32; m++){
    float4 pj = lp[m * 64];
    unsigned lowbits = (unsigned)(2047 - (m*64 + lane));
    float dotA = __fadd_rn(__fadd_rn(__fmul_rn(pa.x, pj.x), __fmul_rn(pa.y, pj.y)), __fmul_rn(pa.z, pj.z));
    float vA = __fsub_rn(__fsub_rn(-pa.w, __fmul_rn(-2.f, dotA)), pj.w);
    unsigned long long pkA = ((unsigned long long)ordf(vA) << 32) | lowbits;
    if (pkA > a3){
      if (pkA > a2){ a3 = a2; if (pkA > a1){ a2 = a1; if (pkA > a0){ a1 = a0; a0 = pkA; } else a1 = pkA; } else a2 = pkA; }
      else a3 = pkA;
    }
    float dotB = __fadd_rn(__fadd_rn(__fmul_rn(pb.x, pj.x), __fmul_rn(pb.y, pj.y)), __fmul_rn(pb.z, pj.z));
    float vB = __fsub_rn(__fsub_rn(-pb.w, __fmul_rn(-2.f, dotB)), pj.w);
    unsigned long long pkB = ((unsigned long long)ordf(vB) << 32) | lowbits;
    if (pkB > b3){
      if (pkB > b2){ b3 = b2; if (pkB > b1){ b2 = b1; if (pkB > b0){ b1 = b0; b0 = pkB; } else b1 = pkB; } else b2 = pkB; }
      else b3 = pkB;
    }
  }
  unsigned outA = 0, outB = 0;
  unsigned long long lastA = ~0ull, lastB = ~0ull;
  for (int kk = 0; kk < KNN; kk++){
    unsigned hvA = (unsigned)(a0 >> 32), hvB = (unsigned)(b0 >> 32);
    unsigned vmA = hvA, vmB = hvB;
    #pragma unroll
    for (int st = 32; st > 0; st >>= 1){
      unsigned oA = (unsigned)__shfl_xor((int)vmA, st, 64);
      unsigned oB = (unsigned)__shfl_xor((int)vmB, st, 64);
      vmA = (oA > vmA) ? oA : vmA;
      vmB = (oB > vmB) ? oB : vmB;
    }
    bool cA = (hvA == vmA), cB = (hvB == vmB);
    unsigned long long mA = __ballot(cA), mB = __ballot(cB);
    unsigned loA, loB;
    if (__popcll(mA) == 1){
      int wl = __ffsll((unsigned long long)mA) - 1;
      loA = (unsigned)__shfl((int)(unsigned)a0, wl, 64);
    } else {
      unsigned cl = cA ? (unsigned)a0 : 0u;
      #pragma unroll
      for (int st = 32; st > 0; st >>= 1){
        unsigned o = (unsigned)__shfl_xor((int)cl, st, 64);
        cl = (o > cl) ? o : cl;
      }
      loA = cl;
    }
    if (__popcll(mB) == 1){
      int wl = __ffsll((unsigned long long)mB) - 1;
      loB = (unsigned)__shfl((int)(unsigned)b0, wl, 64);
    } else {
      unsigned cl = cB ? (unsigned)b0 : 0u;
      #pragma unroll
      for (int st = 32; st > 0; st >>= 1){
        unsigned o = (unsigned)__shfl_xor((int)cl, st, 64);
        cl = (o > cl) ? o : cl;
      }
      loB = cl;
    }
    if (lane == kk){ outA = loA; outB = loB; }
    if (cA && (unsigned)a0 == loA){
      lastA = a0;
      a0 = a1; a1 = a2; a2 = a3; a3 = 0;
      if (a0 == 0){
        unsigned long long best = 0;
        #pragma unroll
        for (int m = 0; m < 32; m++){
          float4 pj = lp[m * 64];
          float dot = __fadd_rn(__fadd_rn(__fmul_rn(pa.x, pj.x), __fmul_rn(pa.y, pj.y)), __fmul_rn(pa.z, pj.z));
          float vv = __fsub_rn(__fsub_rn(-pa.w, __fmul_rn(-2.f, dot)), pj.w);
          unsigned long long pk = ((unsigned long long)ordf(vv) << 32) | (unsigned)(2047 - (m*64 + lane));
          if (pk < lastA && pk > best) best = pk;
        }
        a0 = best;
      }
    }
    if (cB && (unsigned)b0 == loB){
      lastB = b0;
      b0 = b1; b1 = b2; b2 = b3; b3 = 0;
      if (b0 == 0){
        unsigned long long best = 0;
        #pragma unroll
        for (int m = 0; m < 32; m++){
          float4 pj = lp[m * 64];
          float dot = __fadd_rn(__fadd_rn(__fmul_rn(pb.x, pj.x), __fmul_rn(pb.y, pj.y)), __fmul_rn(pb.z, pj.z));
          float vv = __fsub_rn(__fsub_rn(-pb.w, __fmul_rn(-2.f, dot)), pj.w);
          unsigned long long pk = ((unsigned long long)ordf(vv) << 32) | (unsigned)(2047 - (m*64 + lane));
          if (pk < lastB && pk > best) best = pk;
        }
        b0 = best;
      }
    }
  }
  if (lane < KNN){
    idx[row0 * KNN + lane] = 2047 - (int)outA;
    idx[row1 * KNN + lane] = 2047 - (int)outB;
  }
}

// ------------- graph-feature layer: stats pass (p-norm sums per channel, 21 ch) --------
__global__ __launch_bounds__(256) void gf_stats(const float* __restrict__ x, const int* __restrict__ idx,
                                                const float* __restrict__ Wf, double* __restrict__ sums){
  int tid0 = blockIdx.x * 256 + threadIdx.x;
  float s[21], q[21];
  #pragma unroll
  for (int o = 0; o < 21; o++){ s[o] = 0.f; q[o] = 0.f; }
  for (int pix = tid0; pix < BATCH * NP * KNN; pix += 256 * 256){
    int rem = pix / KNN;
    int n = rem & 2047, b = rem >> 11;
    int j = idx[pix];
    const float* xb = x + b * 3 * NP;
    float c0 = xb[n], c1 = xb[NP + n], c2 = xb[2*NP + n];
    float a0 = xb[j], a1 = xb[NP + j], a2 = xb[2*NP + j];
    float r0 = a0 - c0, r1 = a1 - c1, r2 = a2 - c2;
    float g0 = a1*c2 - a2*c1, g1 = a2*c0 - a0*c2, g2 = a0*c1 - a1*c0;
    #pragma unroll
    for (int o = 0; o < 21; o++){
      float w0 = Wf[o*3], w1 = Wf[o*3+1], w2 = Wf[o*3+2];
      float p0 = w0*r0 + w1*c0 + w2*g0;
      float p1 = w0*r1 + w1*c1 + w2*g1;
      float p2 = w0*r2 + w1*c2 + w2*g2;
      float nm = sqrtf(p0*p0 + p1*p1 + p2*p2) + EPSF;
      s[o] += nm; q[o] += nm * nm;
    }
  }
  __shared__ float bs[4][42];
  int w = threadIdx.x >> 6;
  #pragma unroll
  for (int o = 0; o < 21; o++){
    float a = s[o], bb = q[o];
    #pragma unroll
    for (int st = 1; st < 64; st <<= 1){ a += __shfl_xor(a, st, 64); bb += __shfl_xor(bb, st, 64); }
    if ((threadIdx.x & 63) == 0){ bs[w][o] = a; bs[w][21 + o] = bb; }
  }
  __syncthreads();
  if (threadIdx.x < 42){
    float tot = bs[0][threadIdx.x] + bs[1][threadIdx.x] + bs[2][threadIdx.x] + bs[3][threadIdx.x];
    int o = threadIdx.x % 21, sq = threadIdx.x / 21;
    atomicAdd(&sums[2*o + sq], (double)tot);
  }
}

// -------- graph-feature apply + K-pool: thread = (pixel, k); block = 8 px x 40 k -------
__global__ __launch_bounds__(320) void gf_applypool3(const float* __restrict__ x, const int* __restrict__ idx,
    const float* __restrict__ Wf, const float* __restrict__ Wd, const float* __restrict__ Wg,
    const float* __restrict__ mi, unsigned long long* __restrict__ packedGF){
  __shared__ unsigned long long sM[8*21];
  const int tid = threadIdx.x;
  for (int t = tid; t < 168; t += 320) sM[t] = 0ull;
  __syncthreads();
  const int pxl = tid / 40, k = tid - pxl * 40;
  const int px = blockIdx.x * 8 + pxl;
  const int b = px >> 11, n = px & 2047;
  const float* xb = x + b * 3 * NP;
  float c0 = xb[n], c1 = xb[NP + n], c2 = xb[2*NP + n];
  int j = idx[(size_t)px * KNN + k];
  float a0 = xb[j], a1 = xb[NP + j], a2 = xb[2*NP + j];
  float r0 = a0 - c0, r1 = a1 - c1, r2 = a2 - c2;
  float g0 = a1*c2 - a2*c1, g1 = a2*c0 - a0*c2, g2 = a0*c1 - a1*c0;
  float h[21][3];
  #pragma unroll
  for (int o = 0; o < 21; o++){
    float w0 = Wf[o*3], w1 = Wf[o*3+1], w2 = Wf[o*3+2];
    float p0 = w0*r0 + w1*c0 + w2*g0;
    float p1 = w0*r1 + w1*c1 + w2*g1;
    float p2 = w0*r2 + w1*c2 + w2*g2;
    float nm = sqrtf(p0*p0 + p1*p1 + p2*p2) + EPSF;
    float f = (nm - mi[2*o]) * mi[2*o+1] / nm;
    p0 *= f; p1 *= f; p2 *= f;
    float v0 = Wd[o*3], v1 = Wd[o*3+1], v2 = Wd[o*3+2];
    float d0 = v0*r0 + v1*c0 + v2*g0;
    float d1 = v0*r1 + v1*c1 + v2*g1;
    float d2 = v0*r2 + v1*c2 + v2*g2;
    float dot = p0*d0 + p1*d1 + p2*d2;
    float dsq = d0*d0 + d1*d1 + d2*d2;
    float t = dot / (dsq + EPSF);
    h[o][0] = (dot >= 0.f) ? p0 : fmaf(-t, d0, p0);
    h[o][1] = (dot >= 0.f) ? p1 : fmaf(-t, d1, p1);
    h[o][2] = (dot >= 0.f) ? p2 : fmaf(-t, d2, p2);
  }
  #pragma unroll
  for (int o = 0; o < 21; o++){
    float q0 = 0.f, q1 = 0.f, q2 = 0.f;
    #pragma unroll
    for (int c = 0; c < 21; c++){
      float wg = Wg[o*21 + c];
      q0 = fmaf(wg, h[c][0], q0); q1 = fmaf(wg, h[c][1], q1); q2 = fmaf(wg, h[c][2], q2);
    }
    float dp = q0*h[o][0] + q1*h[o][1] + q2*h[o][2];
    unsigned long long pk = ((unsigned long long)ordf(dp) << 32) | (unsigned)(63 - k);
    atomicMax(&sM[pxl*21 + o], pk);
  }
  __syncthreads();
  for (int t = tid; t < 168; t += 320){
    int lpx = t / 21, lo = t - lpx * 21;
    packedGF[(size_t)(blockIdx.x * 8 + lpx) * 21 + lo] = sM[t];
  }
}

// -------- gather winners: recompute h_o for the winning k, store h1 --------------------
__global__ __launch_bounds__(256) void gf_gather(const float* __restrict__ x, const int* __restrict__ idx,
    const float* __restrict__ Wf, const float* __restrict__ Wd, const float* __restrict__ mi,
    const unsigned long long* __restrict__ packedGF, float* __restrict__ h1){
  int t = blockIdx.x * 256 + threadIdx.x;
  if (t >= BATCH * NP * 21) return;
  int px = t / 21, o = t - px * 21;
  int b = px >> 11, n = px & 2047;
  int k = 63 - (int)(packedGF[t] & 0xffffffffu);
  int j = idx[(size_t)px * KNN + k];
  const float* xb = x + b * 3 * NP;
  float c0 = xb[n], c1 = xb[NP + n], c2 = xb[2*NP + n];
  float a0 = xb[j], a1 = xb[NP + j], a2 = xb[2*NP + j];
  float r0 = a0 - c0, r1 = a1 - c1, r2 = a2 - c2;
  float g0 = a1*c2 - a2*c1, g1 = a2*c0 - a0*c2, g2 = a0*c1 - a1*c0;
  float w0 = Wf[o*3], w1 = Wf[o*3+1], w2 = Wf[o*3+2];
  float p0 = w0*r0 + w1*c0 + w2*g0;
  float p1 = w0*r1 + w1*c1 + w2*g1;
  float p2 = w0*r2 + w1*c2 + w2*g2;
  float nm = sqrtf(p0*p0 + p1*p1 + p2*p2) + EPSF;
  float f = (nm - mi[2*o]) * mi[2*o+1] / nm;
  p0 *= f; p1 *= f; p2 *= f;
  float v0 = Wd[o*3], v1 = Wd[o*3+1], v2 = Wd[o*3+2];
  float d0 = v0*r0 + v1*c0 + v2*g0;
  float d1 = v0*r1 + v1*c1 + v2*g1;
  float d2 = v0*r2 + v1*c2 + v2*g2;
  float dot = p0*d0 + p1*d1 + p2*d2;
  float dsq = d0*d0 + d1*d1 + d2*d2;
  float tt = dot / (dsq + EPSF);
  float o0 = (dot >= 0.f) ? p0 : fmaf(-tt, d0, p0);
  float o1 = (dot >= 0.f) ? p1 : fmaf(-tt, d1, p1);
  float o2 = (dot >= 0.f) ? p2 : fmaf(-tt, d2, p2);
  float* dst = h1 + (size_t)((b*21 + o)*3) * NP + n;
  dst[0] = o0; dst[NP] = o1; dst[2*NP] = o2;
}

// ------- VN layer stats, o-chunked register tiling: block = 1024 px x 8 outputs --------
template<int CIN>
__global__ __launch_bounds__(256) void layer_stats2(const float* __restrict__ hin, const float* __restrict__ Wf,
                                                    double* __restrict__ sums, int Co){
  const int px0 = blockIdx.x * 1024;
  const int b = px0 >> 11;
  const int n0 = (px0 & 2047) + (threadIdx.x << 2);
  const int o0 = blockIdx.y * 8;
  const float* hb = hin + (size_t)b * CIN * 3 * NP + n0;
  float p[8][3][4];
  #pragma unroll
  for (int oo = 0; oo < 8; oo++)
    #pragma unroll
    for (int e = 0; e < 3; e++)
      #pragma unroll
      for (int k = 0; k < 4; k++) p[oo][e][k] = 0.f;
  for (int c = 0; c < CIN; c++){
    float4 hv[3];
    #pragma unroll
    for (int e = 0; e < 3; e++) hv[e] = *(const float4*)&hb[(size_t)(c*3 + e) * NP];
    #pragma unroll
    for (int oo = 0; oo < 8; oo++){
      int o = o0 + oo; if (o >= Co) o = Co - 1;
      float wv = Wf[o*CIN + c];
      #pragma unroll
      for (int e = 0; e < 3; e++){
        p[oo][e][0] = fmaf(wv, hv[e].x, p[oo][e][0]);
        p[oo][e][1] = fmaf(wv, hv[e].y, p[oo][e][1]);
        p[oo][e][2] = fmaf(wv, hv[e].z, p[oo][e][2]);
        p[oo][e][3] = fmaf(wv, hv[e].w, p[oo][e][3]);
      }
    }
  }
  float sl[8], ql[8];
  #pragma unroll
  for (int oo = 0; oo < 8; oo++){
    sl[oo] = 0.f; ql[oo] = 0.f;
    #pragma unroll
    for (int k = 0; k < 4; k++){
      float nm = sqrtf(p[oo][0][k]*p[oo][0][k] + p[oo][1][k]*p[oo][1][k] + p[oo][2][k]*p[oo][2][k]) + EPSF;
      sl[oo] += nm; ql[oo] += nm * nm;
    }
  }
  __shared__ float red[4][16];
  int w = threadIdx.x >> 6;
  #pragma unroll
  for (int oo = 0; oo < 8; oo++){
    float sv = sl[oo], qv = ql[oo];
    #pragma unroll
    for (int st = 1; st < 64; st <<= 1){ sv += __shfl_xor(sv, st, 64); qv += __shfl_xor(qv, st, 64); }
    if ((threadIdx.x & 63) == 0){ red[w][oo] = sv; red[w][8 + oo] = qv; }
  }
  __syncthreads();
  if (threadIdx.x < 16){
    float tot = red[0][threadIdx.x] + red[1][threadIdx.x] + red[2][threadIdx.x] + red[3][threadIdx.x];
    int oo = threadIdx.x & 7, isq = threadIdx.x >> 3;
    int o = o0 + oo;
    if (o < Co) atomicAdd(&sums[2*o + isq], (double)tot);
  }
}

// ------- VN layer apply, o-chunked: block = 256 px x 8 outputs, fp32 out ---------------
template<int CIN>
__global__ __launch_bounds__(256) void layer_apply2(const float* __restrict__ hin, const float* __restrict__ Wf,
    const float* __restrict__ Wd, const float* __restrict__ mi, float* __restrict__ hout, int Co){
  const int px = blockIdx.x * 256 + threadIdx.x;
  const int b = px >> 11, n = px & 2047;
  const int o0 = blockIdx.y * 8;
  const float* hb = hin + (size_t)b * CIN * 3 * NP + n;
  float p[8][3], d[8][3];
  #pragma unroll
  for (int oo = 0; oo < 8; oo++)
    #pragma unroll
    for (int e = 0; e < 3; e++){ p[oo][e] = 0.f; d[oo][e] = 0.f; }
  for (int c = 0; c < CIN; c++){
    float h0 = hb[(size_t)(c*3 + 0) * NP];
    float h1 = hb[(size_t)(c*3 + 1) * NP];
    float h2 = hb[(size_t)(c*3 + 2) * NP];
    #pragma unroll
    for (int oo = 0; oo < 8; oo++){
      int o = o0 + oo; if (o >= Co) o = Co - 1;
      float wf = Wf[o*CIN + c], wd = Wd[o*CIN + c];
      p[oo][0] = fmaf(wf, h0, p[oo][0]); p[oo][1] = fmaf(wf, h1, p[oo][1]); p[oo][2] = fmaf(wf, h2, p[oo][2]);
      d[oo][0] = fmaf(wd, h0, d[oo][0]); d[oo][1] = fmaf(wd, h1, d[oo][1]); d[oo][2] = fmaf(wd, h2, d[oo][2]);
    }
  }
  #pragma unroll
  for (int oo = 0; oo < 8; oo++){
    int o = o0 + oo;
    if (o < Co){
      float nm = sqrtf(p[oo][0]*p[oo][0] + p[oo][1]*p[oo][1] + p[oo][2]*p[oo][2]) + EPSF;
      float f = (nm - mi[2*o]) * mi[2*o+1] / nm;
      float p0 = p[oo][0]*f, p1 = p[oo][1]*f, p2 = p[oo][2]*f;
      float dot = p0*d[oo][0] + p1*d[oo][1] + p2*d[oo][2];
      float dsq = d[oo][0]*d[oo][0] + d[oo][1]*d[oo][1] + d[oo][2]*d[oo][2];
      float t = dot / (dsq + EPSF);
      float r0 = (dot >= 0.f) ? p0 : fmaf(-t, d[oo][0], p0);
      float r1 = (dot >= 0.f) ? p1 : fmaf(-t, d[oo][1], p1);
      float r2 = (dot >= 0.f) ? p2 : fmaf(-t, d[oo][2], p2);
      float* dst = hout + (size_t)((b*Co + o)*3) * NP + n;
      dst[0] = r0; dst[NP] = r1; dst[2*NP] = r2;
    }
  }
}

// ------- last VN layer (42->341): o-chunked apply + k-packed bf16 hi/lo output ---------
__global__ __launch_bounds__(256) void layer_apply_l3v2(const float* __restrict__ hin, const float* __restrict__ Wf,
    const float* __restrict__ Wd, const float* __restrict__ mi,
    unsigned short* __restrict__ Hkh, unsigned short* __restrict__ Hkl){
  const int px = blockIdx.x * 256 + threadIdx.x;
  const int b = px >> 11, n = px & 2047;
  const int o0 = blockIdx.y * 8;
  const float* hb = hin + (size_t)b * 42 * 3 * NP + n;
  float r[8][3];
  #pragma unroll
  for (int oo = 0; oo < 8; oo++)
    #pragma unroll
    for (int e = 0; e < 3; e++) r[oo][e] = 0.f;
  if (o0 < 341){
    float p[8][3], d[8][3];
    #pragma unroll
    for (int oo = 0; oo < 8; oo++)
      #pragma unroll
      for (int e = 0; e < 3; e++){ p[oo][e] = 0.f; d[oo][e] = 0.f; }
    for (int c = 0; c < 42; c++){
      float h0 = hb[(size_t)(c*3 + 0) * NP];
      float h1 = hb[(size_t)(c*3 + 1) * NP];
      float h2 = hb[(size_t)(c*3 + 2) * NP];
      #pragma unroll
      for (int oo = 0; oo < 8; oo++){
        int o = o0 + oo; if (o >= 341) o = 340;
        float wf = Wf[o*42 + c], wd = Wd[o*42 + c];
        p[oo][0] = fmaf(wf, h0, p[oo][0]); p[oo][1] = fmaf(wf, h1, p[oo][1]); p[oo][2] = fmaf(wf, h2, p[oo][2]);
        d[oo][0] = fmaf(wd, h0, d[oo][0]); d[oo][1] = fmaf(wd, h1, d[oo][1]); d[oo][2] = fmaf(wd, h2, d[oo][2]);
      }
    }
    #pragma unroll
    for (int oo = 0; oo < 8; oo++){
      int o = o0 + oo;
      if (o < 341){
        float nm = sqrtf(p[oo][0]*p[oo][0] + p[oo][1]*p[oo][1] + p[oo][2]*p[oo][2]) + EPSF;
        float f = (nm - mi[2*o]) * mi[2*o+1] / nm;
        float p0 = p[oo][0]*f, p1 = p[oo][1]*f, p2 = p[oo][2]*f;
        float dot = p0*d[oo][0] + p1*d[oo][1] + p2*d[oo][2];
        float dsq = d[oo][0]*d[oo][0] + d[oo][1]*d[oo][1] + d[oo][2]*d[oo][2];
        float t = dot / (dsq + EPSF);
        r[oo][0] = (dot >= 0.f) ? p0 : fmaf(-t, d[oo][0], p0);
        r[oo][1] = (dot >= 0.f) ? p1 : fmaf(-t, d[oo][1], p1);
        r[oo][2] = (dot >= 0.f) ? p2 : fmaf(-t, d[oo][2], p2);
      }
    }
  }
  #pragma unroll
  for (int e = 0; e < 3; e++){
    unsigned ph[4], pl[4];
    #pragma unroll
    for (int oo = 0; oo < 8; oo++){
      unsigned short hh, ll;
      bsplit(r[oo][e], hh, ll);
      if (!(oo & 1)){ ph[oo>>1] = hh; pl[oo>>1] = ll; }
      else { ph[oo>>1] |= ((unsigned)hh) << 16; pl[oo>>1] |= ((unsigned)ll) << 16; }
    }
    size_t base = ((((size_t)(b*3 + e))*48 + blockIdx.y) * 2048 + n) * 8;
    *(uint4*)(Hkh + base) = make_uint4(ph[0], ph[1], ph[2], ph[3]);
    *(uint4*)(Hkl + base) = make_uint4(pl[0], pl[1], pl[2], pl[3]);
  }
}

__global__ void finalize_stats(const double* __restrict__ sums, float* __restrict__ mi, int Co, double invM){
  int o = blockIdx.x * 64 + threadIdx.x;
  if (o >= Co) return;
  double m = sums[2*o] * invM;
  double v = sums[2*o+1] * invM - m * m;
  if (v < 0.0) v = 0.0;
  mi[2*o] = (float)m;
  mi[2*o+1] = (float)(1.0 / sqrt(v + (double)BNEPS));
}

// ------- split W_pool into k-packed bf16 hi/lo: Wk[cb=0..43][o=0..383][j=0..7] ---------
__global__ __launch_bounds__(256) void wk_kernel(const float* __restrict__ Wp,
    unsigned short* __restrict__ Wkh, unsigned short* __restrict__ Wkl){
  int t = blockIdx.x * 256 + threadIdx.x;
  if (t >= 44*384*8) return;
  int j = t & 7, o = (t >> 3) % 384, cb = t / (384*8);
  int c = cb*8 + j;
  float v = (c < 341 && o < 341) ? Wp[o*341 + c] : 0.f;
  unsigned short h, l;
  bsplit(v, h, l);
  Wkh[t] = h; Wkl[t] = l;
}

// ------------- pool over N via split-bf16 MFMA: D = Wpool @ H; dot; argmax -------------
__global__ __launch_bounds__(256) void pool_mfma(const unsigned short* __restrict__ Wkh,
    const unsigned short* __restrict__ Wkl, const unsigned short* __restrict__ Hkh,
    const unsigned short* __restrict__ Hkl, unsigned long long* __restrict__ packed){
  __shared__ unsigned short sB[2][2][4][64][8];   // [buf][hi/lo][kb][n][j] = 16 KB
  const int b = blockIdx.z, o0 = blockIdx.y * 128, n0 = blockIdx.x * 64;
  const int t = threadIdx.x, w = t >> 6, l = t & 63;
  const int wo = o0 + w * 32;
  const int r = l & 15, g = l >> 4;
  const int skb = t >> 6, sn = t & 63;
  const int ktw = wo >> 5;

  f32x4 acc[2][4], dotv[2][4], hval[2][4];
  #pragma unroll
  for (int s = 0; s < 2; s++)
    #pragma unroll
    for (int nt = 0; nt < 4; nt++){ dotv[s][nt] = (f32x4)0.f; hval[s][nt] = (f32x4)0.f; }

  auto gsrc = [&](const unsigned short* base, int e, int kt) -> const uint4* {
    return (const uint4*)(base + ((((size_t)(b*3 + e))*48 + (size_t)(kt*4 + skb)) * 2048 + n0 + sn) * 8);
  };

  uint4 rg[2];
  rg[0] = *gsrc(Hkh, 0, 0);
  rg[1] = *gsrc(Hkl, 0, 0);

  for (int ek = 0; ek < 33; ek++){
    const int e = ek / 11, kt = ek - e*11, buf = ek & 1;
    *(uint4*)&sB[buf][0][skb][sn][0] = rg[0];
    *(uint4*)&sB[buf][1][skb][sn][0] = rg[1];
    __syncthreads();
    if (ek < 32){
      int e2 = (ek+1) / 11, kt2 = (ek+1) - e2*11;
      rg[0] = *gsrc(Hkh, e2, kt2);
      rg[1] = *gsrc(Hkl, e2, kt2);
    }
    if (kt == 0){
      #pragma unroll
      for (int s = 0; s < 2; s++)
        #pragma unroll
        for (int nt = 0; nt < 4; nt++) acc[s][nt] = (f32x4)0.f;
    }
    short8 ah[2], al[2];
    #pragma unroll
    for (int s = 0; s < 2; s++){
      size_t aoff = (((size_t)(kt*4 + g)) * 384 + (wo + s*16 + r)) * 8;
      ah[s] = *(const short8*)(Wkh + aoff);
      al[s] = *(const short8*)(Wkl + aoff);
    }
    #pragma unroll
    for (int nt = 0; nt < 4; nt++){
      short8 bh = *(const short8*)&sB[buf][0][g][nt*16 + r][0];
      short8 bl = *(const short8*)&sB[buf][1][g][nt*16 + r][0];
      #pragma unroll
      for (int s = 0; s < 2; s++){
        acc[s][nt] = __builtin_amdgcn_mfma_f32_16x16x32_bf16(ah[s], bh, acc[s][nt], 0, 0, 0);
        acc[s][nt] = __builtin_amdgcn_mfma_f32_16x16x32_bf16(ah[s], bl, acc[s][nt], 0, 0, 0);
        acc[s][nt] = __builtin_amdgcn_mfma_f32_16x16x32_bf16(al[s], bh, acc[s][nt], 0, 0, 0);
      }
    }
    if (kt == ktw){
      #pragma unroll
      for (int s = 0; s < 2; s++){
        #pragma unroll
        for (int jj = 0; jj < 4; jj++){
          int oin = s*16 + g*4 + jj;
          #pragma unroll
          for (int nt = 0; nt < 4; nt++){
            hval[s][nt][jj] = bf2f(sB[buf][0][oin>>3][nt*16 + r][oin&7])
                            + bf2f(sB[buf][1][oin>>3][nt*16 + r][oin&7]);
          }
        }
      }
    }
    __syncthreads();
    if (kt == 10){
      #pragma unroll
      for (int s = 0; s < 2; s++)
        #pragma unroll
        for (int nt = 0; nt < 4; nt++)
          #pragma unroll
          for (int jj = 0; jj < 4; jj++)
            dotv[s][nt][jj] += acc[s][nt][jj] * hval[s][nt][jj];
    }
  }
  #pragma unroll
  for (int s = 0; s < 2; s++){
    #pragma unroll
    for (int j = 0; j < 4; j++){
      int o = wo + s*16 + g*4 + j;
      unsigned long long best = 0;
      #pragma unroll
      for (int nt = 0; nt < 4; nt++){
        int n = n0 + nt*16 + r;
        unsigned long long pk = ((unsigned long long)ordf(dotv[s][nt][j]) << 32) | (unsigned)(2047 - n);
        if (pk > best) best = pk;
      }
      #pragma unroll
      for (int st = 1; st < 16; st <<= 1){
        unsigned long long ob = __shfl_xor(best, st, 64);
        if (ob > best) best = ob;
      }
      if (r == 0 && o < 341) atomicMax(&packed[b*341 + o], best);
    }
  }
}

__global__ void pool_gather(const unsigned long long* __restrict__ packed,
                            const unsigned short* __restrict__ Hkh, const unsigned short* __restrict__ Hkl,
                            float* __restrict__ pooled){
  int t = blockIdx.x * 256 + threadIdx.x;
  if (t >= BATCH * 341) return;
  int n = 2047 - (int)(packed[t] & 0xffffffffu);
  int b = t / 341, o = t % 341;
  #pragma unroll
  for (int e = 0; e < 3; e++){
    size_t hb = ((((size_t)(b*3 + e))*48 + (o >> 3)) * 2048 + n) * 8 + (o & 7);
    pooled[t*3 + e] = bf2f(Hkh[hb]) + bf2f(Hkl[hb]);
  }
}

// -------- fully-connected VN layer (B=8 pixels, per-channel bn over B) -----------------
__global__ __launch_bounds__(64) void flayer(const float* __restrict__ in, const float* __restrict__ Wf,
    const float* __restrict__ Wd, float* __restrict__ out, int Cin, int Co){
  int o = blockIdx.x, lane = threadIdx.x;
  float pv[24], dv[24];
  #pragma unroll
  for (int be = 0; be < 24; be++){ pv[be] = 0.f; dv[be] = 0.f; }
  for (int c = lane; c < Cin; c += 64){
    float wf = Wf[o*Cin + c], wd = Wd[o*Cin + c];
    #pragma unroll
    for (int bb = 0; bb < 8; bb++){
      #pragma unroll
      for (int e = 0; e < 3; e++){
        float hv = in[(bb*Cin + c)*3 + e];
        pv[bb*3+e] = fmaf(wf, hv, pv[bb*3+e]);
        dv[bb*3+e] = fmaf(wd, hv, dv[bb*3+e]);
      }
    }
  }
  #pragma unroll
  for (int be = 0; be < 24; be++){
    #pragma unroll
    for (int st = 1; st < 64; st <<= 1){
      pv[be] += __shfl_xor(pv[be], st, 64);
      dv[be] += __shfl_xor(dv[be], st, 64);
    }
  }
  float nm[8], dotb[8], dsqb[8];
  float mean = 0.f;
  #pragma unroll
  for (int bb = 0; bb < 8; bb++){
    nm[bb] = sqrtf(pv[bb*3]*pv[bb*3] + pv[bb*3+1]*pv[bb*3+1] + pv[bb*3+2]*pv[bb*3+2]) + EPSF;
    mean += nm[bb];
  }
  mean *= 0.125f;
  float var = 0.f;
  #pragma unroll
  for (int bb = 0; bb < 8; bb++){ float dvv = nm[bb] - mean; var += dvv * dvv; }
  var *= 0.125f;
  float istd = 1.f / sqrtf(var + BNEPS);
  #pragma unroll
  for (int bb = 0; bb < 8; bb++){
    float f = (nm[bb] - mean) * istd / nm[bb];
    dotb[bb] = f * (pv[bb*3]*dv[bb*3] + pv[bb*3+1]*dv[bb*3+1] + pv[bb*3+2]*dv[bb*3+2]);
    dsqb[bb] = dv[bb*3]*dv[bb*3] + dv[bb*3+1]*dv[bb*3+1] + dv[bb*3+2]*dv[bb*3+2];
  }
  #pragma unroll
  for (int be = 0; be < 24; be++){
    if (lane == be){
      int bb = be / 3;
      float f = (nm[bb] - mean) * istd / nm[bb];
      float pe = pv[be] * f;
      float t = dotb[bb] / (dsqb[bb] + EPSF);
      float res = (dotb[bb] >= 0.f) ? pe : fmaf(-t, dv[be], pe);
      out[(bb*Co + o)*3 + (be % 3)] = res;
    }
  }
}

__global__ void final_lin(const float* __restrict__ in, const float* __restrict__ W, float* __restrict__ out){
  int t = threadIdx.x;
  if (t >= 72) return;
  int b = t / 9, o = (t % 9) / 3, e = t % 3;
  float s = 0.f;
  for (int c = 0; c < 85; c++) s = fmaf(W[o*85 + c], in[(b*85 + c)*3 + e], s);
  out[t] = s;
}

// --------------------------------- launcher -------------------------------------------
extern "C" void kernel_launch(void* const* d_in, const int* in_sizes, int n_in,
                              void* d_out, int out_size, void* d_ws, size_t ws_size,
                              hipStream_t stream){
  const float* x   = (const float*)d_in[0];
  const float* Wpf = (const float*)d_in[1];
  const float* Wpd = (const float*)d_in[2];
  const float* Wg  = (const float*)d_in[3];
  const float* W1f = (const float*)d_in[4];
  const float* W1d = (const float*)d_in[5];
  const float* W2f = (const float*)d_in[6];
  const float* W2d = (const float*)d_in[7];
  const float* W3f = (const float*)d_in[8];
  const float* W3d = (const float*)d_in[9];
  const float* Wpool = (const float*)d_in[10];
  const float* Wf1f = (const float*)d_in[11];
  const float* Wf1d = (const float*)d_in[12];
  const float* Wf2f = (const float*)d_in[13];
  const float* Wf2d = (const float*)d_in[14];
  const float* Wf3  = (const float*)d_in[15];
  float* out = (float*)d_out;

  char* ws = (char*)d_ws;
  size_t off = 0;
  int*   idx  = (int*)(ws + off);             off += (size_t)BATCH*NP*KNN*4;
  unsigned long long* packedGF = (unsigned long long*)(ws + off); off += (size_t)BATCH*NP*21*8;
  float* h1  = (float*)(ws + off);            off += (size_t)BATCH*21*3*NP*4;
  float* h2  = (float*)(ws + off);            off += (size_t)BATCH*21*3*NP*4;
  float* h3  = (float*)(ws + off);            off += (size_t)BATCH*42*3*NP*4;
  unsigned short* Hkh = (unsigned short*)(ws + off); off += (size_t)BATCH*3*48*NP*8*2;
  unsigned short* Hkl = (unsigned short*)(ws + off); off += (size_t)BATCH*3*48*NP*8*2;
  unsigned short* Wkh = (unsigned short*)(ws + off); off += (size_t)44*384*8*2;
  unsigned short* Wkl = (unsigned short*)(ws + off); off += (size_t)44*384*8*2;
  char*  zbase = ws + off;
  double* sums_gf = (double*)(ws + off);      off += 8192;
  double* sums_l1 = (double*)(ws + off);      off += 8192;
  double* sums_l2 = (double*)(ws + off);      off += 8192;
  double* sums_l3 = (double*)(ws + off);      off += 8192;
  unsigned long long* packed = (unsigned long long*)(ws + off); off += 24576;
  size_t zbytes = (ws + off) - zbase;
  float* mi_gf = (float*)(ws + off);          off += 1024;
  float* mi_l1 = (float*)(ws + off);          off += 1024;
  float* mi_l2 = (float*)(ws + off);          off += 1024;
  float* mi_l3 = (float*)(ws + off);          off += 4096;
  float* pooled = (float*)(ws + off);         off += (size_t)BATCH*341*3*4 + 32;
  float* h5 = (float*)(ws + off);             off += (size_t)BATCH*170*3*4 + 32;
  float* h6 = (float*)(ws + off);             off += (size_t)BATCH*85*3*4 + 32;

  hipMemsetAsync(zbase, 0, zbytes, stream);

  knn_kernel<<<BATCH*NP/8, 256, 0, stream>>>(x, idx);
  wk_kernel<<<(44*384*8 + 255)/256, 256, 0, stream>>>(Wpool, Wkh, Wkl);

  gf_stats<<<256, 256, 0, stream>>>(x, idx, Wpf, sums_gf);
  finalize_stats<<<1, 64, 0, stream>>>(sums_gf, mi_gf, 21, 1.0 / (double)(BATCH*NP*KNN));
  gf_applypool3<<<BATCH*NP/8, 320, 0, stream>>>(x, idx, Wpf, Wpd, Wg, mi_gf, packedGF);
  gf_gather<<<(BATCH*NP*21 + 255)/256, 256, 0, stream>>>(x, idx, Wpf, Wpd, mi_gf, packedGF, h1);

  layer_stats2<21><<<dim3(16,3), 256, 0, stream>>>(h1, W1f, sums_l1, 21);
  finalize_stats<<<1, 64, 0, stream>>>(sums_l1, mi_l1, 21, 1.0 / (double)(BATCH*NP));
  layer_apply2<21><<<dim3(64,3), 256, 0, stream>>>(h1, W1f, W1d, mi_l1, h2, 21);

  layer_stats2<21><<<dim3(16,6), 256, 0, stream>>>(h2, W2f, sums_l2, 42);
  finalize_stats<<<1, 64, 0, stream>>>(sums_l2, mi_l2, 42, 1.0 / (double)(BATCH*NP));
  layer_apply2<21><<<dim3(64,6), 256, 0, stream>>>(h2, W2f, W2d, mi_l2, h3, 42);

  layer_stats2<42><<<dim3(16,43), 256, 0, stream>>>(h3, W3f, sums_l3, 341);
  finalize_stats<<<6, 64, 0, stream>>>(sums_l3, mi_l3, 341, 1.0 / (double)(BATCH*NP));
  layer_apply_l3v2<<<dim3(64,44), 256, 0, stream>>>(h3, W3f, W3d, mi_l3, Hkh, Hkl);

  pool_mfma<<<dim3(32, 3, BATCH), 256, 0, stream>>>(Wkh, Wkl, Hkh, Hkl, packed);
  pool_gather<<<(BATCH*341 + 255)/256, 256, 0, stream>>>(packed, Hkh, Hkl, pooled);

  flayer<<<170, 64, 0, stream>>>(pooled, Wf1f, Wf1d, h5, 341, 170);
  flayer<<<85, 64, 0, stream>>>(h5, Wf2f, Wf2d, h6, 170, 85);
  final_lin<<<1, 128, 0, stream>>>(h6, Wf3, out);
}

// Round 12
// 469.907 us; speedup vs baseline: 1.3379x; 1.0446x over previous
//
#include <hip/hip_runtime.h>

#define NP 2048
#define BATCH 8
#define KNN 40
#define EPSF 1e-6f
#define BNEPS 1e-5f

typedef __attribute__((ext_vector_type(8))) short short8;
typedef __attribute__((ext_vector_type(4))) float f32x4;

__device__ __forceinline__ unsigned ordf(float v){
  unsigned u = __float_as_uint(v);
  return (u & 0x80000000u) ? ~u : (u | 0x80000000u);
}

// split fp32 -> bf16 hi (RNE) + bf16 lo (RNE of residual)
__device__ __forceinline__ void bsplit(float v, unsigned short &h, unsigned short &l){
  unsigned u = __float_as_uint(v);
  unsigned hu = (u + 0x7fffu + ((u >> 16) & 1u)) >> 16;
  h = (unsigned short)hu;
  float r = v - __uint_as_float(hu << 16);
  unsigned u2 = __float_as_uint(r);
  l = (unsigned short)((u2 + 0x7fffu + ((u2 >> 16) & 1u)) >> 16);
}

__device__ __forceinline__ float bf2f(unsigned short h){
  return __uint_as_float(((unsigned)h) << 16);
}

// ---------------- KNN: exact top-40, paired-row ILP variant (R11, known-good) ----------
__global__ __launch_bounds__(256) void knn_kernel(const float* __restrict__ x, int* __restrict__ idx){
  __shared__ float4 sP[NP];   // 32 KB
  int tid = threadIdx.x;
  int w = tid >> 6, lane = tid & 63;
  int row0 = blockIdx.x * 8 + w * 2, row1 = row0 + 1;
  int b = row0 >> 11;
  int i0 = row0 & 2047, i1 = row1 & 2047;
  const float* xb = x + b * 3 * NP;
  for (int t = tid; t < NP; t += 256){
    float a = xb[t], c = xb[NP + t], d = xb[2*NP + t];
    float xx = __fadd_rn(__fadd_rn(__fmul_rn(a,a), __fmul_rn(c,c)), __fmul_rn(d,d));
    sP[t] = make_float4(a, c, d, xx);
  }
  __syncthreads();
  float4 pa = sP[i0];
  float4 pb = sP[i1];
  const float4* lp = &sP[lane];
  unsigned long long a0 = 0, a1 = 0, a2 = 0, a3 = 0;
  unsigned long long b0 = 0, b1 = 0, b2 = 0, b3 = 0;
  #pragma unroll
  for (int m = 0; m < 32; m++){
    float4 pj = lp[m * 64];
    unsigned lowbits = (unsigned)(2047 - (m*64 + lane));
    float dotA = __fadd_rn(__fadd_rn(__fmul_rn(pa.x, pj.x), __fmul_rn(pa.y, pj.y)), __fmul_rn(pa.z, pj.z));
    float vA = __fsub_rn(__fsub_rn(-pa.w, __fmul_rn(-2.f, dotA)), pj.w);
    unsigned long long pkA = ((unsigned long long)ordf(vA) << 32) | lowbits;
    if (pkA > a3){
      if (pkA > a2){ a3 = a2; if (pkA > a1){ a2 = a1; if (pkA > a0){ a1 = a0; a0 = pkA; } else a1 = pkA; } else a2 = pkA; }
      else a3 = pkA;
    }
    float dotB = __fadd_rn(__fadd_rn(__fmul_rn(pb.x, pj.x), __fmul_rn(pb.y, pj.y)), __fmul_rn(pb.z, pj.z));
    float vB = __fsub_rn(__fsub_rn(-pb.w, __fmul_rn(-2.f, dotB)), pj.w);
    unsigned long long pkB = ((unsigned long long)ordf(vB) << 32) | lowbits;
    if (pkB > b3){
      if (pkB > b2){ b3 = b2; if (pkB > b1){ b2 = b1; if (pkB > b0){ b1 = b0; b0 = pkB; } else b1 = pkB; } else b2 = pkB; }
      else b3 = pkB;
    }
  }
  unsigned outA = 0, outB = 0;
  unsigned long long lastA = ~0ull, lastB = ~0ull;
  for (int kk = 0; kk < KNN; kk++){
    unsigned hvA = (unsigned)(a0 >> 32), hvB = (unsigned)(b0 >> 32);
    unsigned vmA = hvA, vmB = hvB;
    #pragma unroll
    for (int st = 32; st > 0; st >>= 1){
      unsigned oA = (unsigned)__shfl_xor((int)vmA, st, 64);
      unsigned oB = (unsigned)__shfl_xor((int)vmB, st, 64);
      vmA = (oA > vmA) ? oA : vmA;
      vmB = (oB > vmB) ? oB : vmB;
    }
    bool cA = (hvA == vmA), cB = (hvB == vmB);
    unsigned long long mA = __ballot(cA), mB = __ballot(cB);
    unsigned loA, loB;
    if (__popcll(mA) == 1){
      int wl = __ffsll((unsigned long long)mA) - 1;
      loA = (unsigned)__shfl((int)(unsigned)a0, wl, 64);
    } else {
      unsigned cl = cA ? (unsigned)a0 : 0u;
      #pragma unroll
      for (int st = 32; st > 0; st >>= 1){
        unsigned o = (unsigned)__shfl_xor((int)cl, st, 64);
        cl = (o > cl) ? o : cl;
      }
      loA = cl;
    }
    if (__popcll(mB) == 1){
      int wl = __ffsll((unsigned long long)mB) - 1;
      loB = (unsigned)__shfl((int)(unsigned)b0, wl, 64);
    } else {
      unsigned cl = cB ? (unsigned)b0 : 0u;
      #pragma unroll
      for (int st = 32; st > 0; st >>= 1){
        unsigned o = (unsigned)__shfl_xor((int)cl, st, 64);
        cl = (o > cl) ? o : cl;
      }
      loB = cl;
    }
    if (lane == kk){ outA = loA; outB = loB; }
    if (cA && (unsigned)a0 == loA){
      lastA = a0;
      a0 = a1; a1 = a2; a2 = a3; a3 = 0;
      if (a0 == 0){
        unsigned long long best = 0;
        #pragma unroll
        for (int m = 0; m < 32; m++){
          float4 pj = lp[m * 64];
          float dot = __fadd_rn(__fadd_rn(__fmul_rn(pa.x, pj.x), __fmul_rn(pa.y, pj.y)), __fmul_rn(pa.z, pj.z));
          float vv = __fsub_rn(__fsub_rn(-pa.w, __fmul_rn(-2.f, dot)), pj.w);
          unsigned long long pk = ((unsigned long long)ordf(vv) << 32) | (unsigned)(2047 - (m*64 + lane));
          if (pk < lastA && pk > best) best = pk;
        }
        a0 = best;
      }
    }
    if (cB && (unsigned)b0 == loB){
      lastB = b0;
      b0 = b1; b1 = b2; b2 = b3; b3 = 0;
      if (b0 == 0){
        unsigned long long best = 0;
        #pragma unroll
        for (int m = 0; m < 32; m++){
          float4 pj = lp[m * 64];
          float dot = __fadd_rn(__fadd_rn(__fmul_rn(pb.x, pj.x), __fmul_rn(pb.y, pj.y)), __fmul_rn(pb.z, pj.z));
          float vv = __fsub_rn(__fsub_rn(-pb.w, __fmul_rn(-2.f, dot)), pj.w);
          unsigned long long pk = ((unsigned long long)ordf(vv) << 32) | (unsigned)(2047 - (m*64 + lane));
          if (pk < lastB && pk > best) best = pk;
        }
        b0 = best;
      }
    }
  }
  if (lane < KNN){
    idx[row0 * KNN + lane] = 2047 - (int)outA;
    idx[row1 * KNN + lane] = 2047 - (int)outB;
  }
}

// ------------- graph-feature layer: stats pass (p-norm sums per channel, 21 ch) --------
__global__ __launch_bounds__(256) void gf_stats(const float* __restrict__ x, const int* __restrict__ idx,
                                                const float* __restrict__ Wf, double* __restrict__ sums){
  int tid0 = blockIdx.x * 256 + threadIdx.x;
  float s[21], q[21];
  #pragma unroll
  for (int o = 0; o < 21; o++){ s[o] = 0.f; q[o] = 0.f; }
  for (int pix = tid0; pix < BATCH * NP * KNN; pix += 256 * 256){
    int rem = pix / KNN;
    int n = rem & 2047, b = rem >> 11;
    int j = idx[pix];
    const float* xb = x + b * 3 * NP;
    float c0 = xb[n], c1 = xb[NP + n], c2 = xb[2*NP + n];
    float a0 = xb[j], a1 = xb[NP + j], a2 = xb[2*NP + j];
    float r0 = a0 - c0, r1 = a1 - c1, r2 = a2 - c2;
    float g0 = a1*c2 - a2*c1, g1 = a2*c0 - a0*c2, g2 = a0*c1 - a1*c0;
    #pragma unroll
    for (int o = 0; o < 21; o++){
      float w0 = Wf[o*3], w1 = Wf[o*3+1], w2 = Wf[o*3+2];
      float p0 = w0*r0 + w1*c0 + w2*g0;
      float p1 = w0*r1 + w1*c1 + w2*g1;
      float p2 = w0*r2 + w1*c2 + w2*g2;
      float nm = sqrtf(p0*p0 + p1*p1 + p2*p2) + EPSF;
      s[o] += nm; q[o] += nm * nm;
    }
  }
  __shared__ float bs[4][42];
  int w = threadIdx.x >> 6;
  #pragma unroll
  for (int o = 0; o < 21; o++){
    float a = s[o], bb = q[o];
    #pragma unroll
    for (int st = 1; st < 64; st <<= 1){ a += __shfl_xor(a, st, 64); bb += __shfl_xor(bb, st, 64); }
    if ((threadIdx.x & 63) == 0){ bs[w][o] = a; bs[w][21 + o] = bb; }
  }
  __syncthreads();
  if (threadIdx.x < 42){
    float tot = bs[0][threadIdx.x] + bs[1][threadIdx.x] + bs[2][threadIdx.x] + bs[3][threadIdx.x];
    int o = threadIdx.x % 21, sq = threadIdx.x / 21;
    atomicAdd(&sums[2*o + sq], (double)tot);
  }
}

// -------- graph-feature apply + K-pool: thread = (pixel, k); block = 8 px x 40 k -------
__global__ __launch_bounds__(320) void gf_applypool3(const float* __restrict__ x, const int* __restrict__ idx,
    const float* __restrict__ Wf, const float* __restrict__ Wd, const float* __restrict__ Wg,
    const float* __restrict__ mi, unsigned long long* __restrict__ packedGF){
  __shared__ unsigned long long sM[8*21];
  const int tid = threadIdx.x;
  for (int t = tid; t < 168; t += 320) sM[t] = 0ull;
  __syncthreads();
  const int pxl = tid / 40, k = tid - pxl * 40;
  const int px = blockIdx.x * 8 + pxl;
  const int b = px >> 11, n = px & 2047;
  const float* xb = x + b * 3 * NP;
  float c0 = xb[n], c1 = xb[NP + n], c2 = xb[2*NP + n];
  int j = idx[(size_t)px * KNN + k];
  float a0 = xb[j], a1 = xb[NP + j], a2 = xb[2*NP + j];
  float r0 = a0 - c0, r1 = a1 - c1, r2 = a2 - c2;
  float g0 = a1*c2 - a2*c1, g1 = a2*c0 - a0*c2, g2 = a0*c1 - a1*c0;
  float h[21][3];
  #pragma unroll
  for (int o = 0; o < 21; o++){
    float w0 = Wf[o*3], w1 = Wf[o*3+1], w2 = Wf[o*3+2];
    float p0 = w0*r0 + w1*c0 + w2*g0;
    float p1 = w0*r1 + w1*c1 + w2*g1;
    float p2 = w0*r2 + w1*c2 + w2*g2;
    float nm = sqrtf(p0*p0 + p1*p1 + p2*p2) + EPSF;
    float f = (nm - mi[2*o]) * mi[2*o+1] / nm;
    p0 *= f; p1 *= f; p2 *= f;
    float v0 = Wd[o*3], v1 = Wd[o*3+1], v2 = Wd[o*3+2];
    float d0 = v0*r0 + v1*c0 + v2*g0;
    float d1 = v0*r1 + v1*c1 + v2*g1;
    float d2 = v0*r2 + v1*c2 + v2*g2;
    float dot = p0*d0 + p1*d1 + p2*d2;
    float dsq = d0*d0 + d1*d1 + d2*d2;
    float t = dot / (dsq + EPSF);
    h[o][0] = (dot >= 0.f) ? p0 : fmaf(-t, d0, p0);
    h[o][1] = (dot >= 0.f) ? p1 : fmaf(-t, d1, p1);
    h[o][2] = (dot >= 0.f) ? p2 : fmaf(-t, d2, p2);
  }
  #pragma unroll
  for (int o = 0; o < 21; o++){
    float q0 = 0.f, q1 = 0.f, q2 = 0.f;
    #pragma unroll
    for (int c = 0; c < 21; c++){
      float wg = Wg[o*21 + c];
      q0 = fmaf(wg, h[c][0], q0); q1 = fmaf(wg, h[c][1], q1); q2 = fmaf(wg, h[c][2], q2);
    }
    float dp = q0*h[o][0] + q1*h[o][1] + q2*h[o][2];
    unsigned long long pk = ((unsigned long long)ordf(dp) << 32) | (unsigned)(63 - k);
    atomicMax(&sM[pxl*21 + o], pk);
  }
  __syncthreads();
  for (int t = tid; t < 168; t += 320){
    int lpx = t / 21, lo = t - lpx * 21;
    packedGF[(size_t)(blockIdx.x * 8 + lpx) * 21 + lo] = sM[t];
  }
}

// -------- gather winners: recompute h_o for the winning k, store h1 --------------------
__global__ __launch_bounds__(256) void gf_gather(const float* __restrict__ x, const int* __restrict__ idx,
    const float* __restrict__ Wf, const float* __restrict__ Wd, const float* __restrict__ mi,
    const unsigned long long* __restrict__ packedGF, float* __restrict__ h1){
  int t = blockIdx.x * 256 + threadIdx.x;
  if (t >= BATCH * NP * 21) return;
  int px = t / 21, o = t - px * 21;
  int b = px >> 11, n = px & 2047;
  int k = 63 - (int)(packedGF[t] & 0xffffffffu);
  int j = idx[(size_t)px * KNN + k];
  const float* xb = x + b * 3 * NP;
  float c0 = xb[n], c1 = xb[NP + n], c2 = xb[2*NP + n];
  float a0 = xb[j], a1 = xb[NP + j], a2 = xb[2*NP + j];
  float r0 = a0 - c0, r1 = a1 - c1, r2 = a2 - c2;
  float g0 = a1*c2 - a2*c1, g1 = a2*c0 - a0*c2, g2 = a0*c1 - a1*c0;
  float w0 = Wf[o*3], w1 = Wf[o*3+1], w2 = Wf[o*3+2];
  float p0 = w0*r0 + w1*c0 + w2*g0;
  float p1 = w0*r1 + w1*c1 + w2*g1;
  float p2 = w0*r2 + w1*c2 + w2*g2;
  float nm = sqrtf(p0*p0 + p1*p1 + p2*p2) + EPSF;
  float f = (nm - mi[2*o]) * mi[2*o+1] / nm;
  p0 *= f; p1 *= f; p2 *= f;
  float v0 = Wd[o*3], v1 = Wd[o*3+1], v2 = Wd[o*3+2];
  float d0 = v0*r0 + v1*c0 + v2*g0;
  float d1 = v0*r1 + v1*c1 + v2*g1;
  float d2 = v0*r2 + v1*c2 + v2*g2;
  float dot = p0*d0 + p1*d1 + p2*d2;
  float dsq = d0*d0 + d1*d1 + d2*d2;
  float tt = dot / (dsq + EPSF);
  float o0 = (dot >= 0.f) ? p0 : fmaf(-tt, d0, p0);
  float o1 = (dot >= 0.f) ? p1 : fmaf(-tt, d1, p1);
  float o2 = (dot >= 0.f) ? p2 : fmaf(-tt, d2, p2);
  float* dst = h1 + (size_t)((b*21 + o)*3) * NP + n;
  dst[0] = o0; dst[NP] = o1; dst[2*NP] = o2;
}

// ------- VN layer stats, o-chunked register tiling: block = 1024 px x 8 outputs --------
template<int CIN>
__global__ __launch_bounds__(256) void layer_stats2(const float* __restrict__ hin, const float* __restrict__ Wf,
                                                    double* __restrict__ sums, int Co){
  const int px0 = blockIdx.x * 1024;
  const int b = px0 >> 11;
  const int n0 = (px0 & 2047) + (threadIdx.x << 2);
  const int o0 = blockIdx.y * 8;
  const float* hb = hin + (size_t)b * CIN * 3 * NP + n0;
  float p[8][3][4];
  #pragma unroll
  for (int oo = 0; oo < 8; oo++)
    #pragma unroll
    for (int e = 0; e < 3; e++)
      #pragma unroll
      for (int k = 0; k < 4; k++) p[oo][e][k] = 0.f;
  for (int c = 0; c < CIN; c++){
    float4 hv[3];
    #pragma unroll
    for (int e = 0; e < 3; e++) hv[e] = *(const float4*)&hb[(size_t)(c*3 + e) * NP];
    #pragma unroll
    for (int oo = 0; oo < 8; oo++){
      int o = o0 + oo; if (o >= Co) o = Co - 1;
      float wv = Wf[o*CIN + c];
      #pragma unroll
      for (int e = 0; e < 3; e++){
        p[oo][e][0] = fmaf(wv, hv[e].x, p[oo][e][0]);
        p[oo][e][1] = fmaf(wv, hv[e].y, p[oo][e][1]);
        p[oo][e][2] = fmaf(wv, hv[e].z, p[oo][e][2]);
        p[oo][e][3] = fmaf(wv, hv[e].w, p[oo][e][3]);
      }
    }
  }
  float sl[8], ql[8];
  #pragma unroll
  for (int oo = 0; oo < 8; oo++){
    sl[oo] = 0.f; ql[oo] = 0.f;
    #pragma unroll
    for (int k = 0; k < 4; k++){
      float nm = sqrtf(p[oo][0][k]*p[oo][0][k] + p[oo][1][k]*p[oo][1][k] + p[oo][2][k]*p[oo][2][k]) + EPSF;
      sl[oo] += nm; ql[oo] += nm * nm;
    }
  }
  __shared__ float red[4][16];
  int w = threadIdx.x >> 6;
  #pragma unroll
  for (int oo = 0; oo < 8; oo++){
    float sv = sl[oo], qv = ql[oo];
    #pragma unroll
    for (int st = 1; st < 64; st <<= 1){ sv += __shfl_xor(sv, st, 64); qv += __shfl_xor(qv, st, 64); }
    if ((threadIdx.x & 63) == 0){ red[w][oo] = sv; red[w][8 + oo] = qv; }
  }
  __syncthreads();
  if (threadIdx.x < 16){
    float tot = red[0][threadIdx.x] + red[1][threadIdx.x] + red[2][threadIdx.x] + red[3][threadIdx.x];
    int oo = threadIdx.x & 7, isq = threadIdx.x >> 3;
    int o = o0 + oo;
    if (o < Co) atomicAdd(&sums[2*o + isq], (double)tot);
  }
}

// ------- VN layer apply, o-chunked: block = 256 px x 8 outputs, fp32 out ---------------
template<int CIN>
__global__ __launch_bounds__(256) void layer_apply2(const float* __restrict__ hin, const float* __restrict__ Wf,
    const float* __restrict__ Wd, const float* __restrict__ mi, float* __restrict__ hout, int Co){
  const int px = blockIdx.x * 256 + threadIdx.x;
  const int b = px >> 11, n = px & 2047;
  const int o0 = blockIdx.y * 8;
  const float* hb = hin + (size_t)b * CIN * 3 * NP + n;
  float p[8][3], d[8][3];
  #pragma unroll
  for (int oo = 0; oo < 8; oo++)
    #pragma unroll
    for (int e = 0; e < 3; e++){ p[oo][e] = 0.f; d[oo][e] = 0.f; }
  for (int c = 0; c < CIN; c++){
    float h0 = hb[(size_t)(c*3 + 0) * NP];
    float h1 = hb[(size_t)(c*3 + 1) * NP];
    float h2 = hb[(size_t)(c*3 + 2) * NP];
    #pragma unroll
    for (int oo = 0; oo < 8; oo++){
      int o = o0 + oo; if (o >= Co) o = Co - 1;
      float wf = Wf[o*CIN + c], wd = Wd[o*CIN + c];
      p[oo][0] = fmaf(wf, h0, p[oo][0]); p[oo][1] = fmaf(wf, h1, p[oo][1]); p[oo][2] = fmaf(wf, h2, p[oo][2]);
      d[oo][0] = fmaf(wd, h0, d[oo][0]); d[oo][1] = fmaf(wd, h1, d[oo][1]); d[oo][2] = fmaf(wd, h2, d[oo][2]);
    }
  }
  #pragma unroll
  for (int oo = 0; oo < 8; oo++){
    int o = o0 + oo;
    if (o < Co){
      float nm = sqrtf(p[oo][0]*p[oo][0] + p[oo][1]*p[oo][1] + p[oo][2]*p[oo][2]) + EPSF;
      float f = (nm - mi[2*o]) * mi[2*o+1] / nm;
      float p0 = p[oo][0]*f, p1 = p[oo][1]*f, p2 = p[oo][2]*f;
      float dot = p0*d[oo][0] + p1*d[oo][1] + p2*d[oo][2];
      float dsq = d[oo][0]*d[oo][0] + d[oo][1]*d[oo][1] + d[oo][2]*d[oo][2];
      float t = dot / (dsq + EPSF);
      float r0 = (dot >= 0.f) ? p0 : fmaf(-t, d[oo][0], p0);
      float r1 = (dot >= 0.f) ? p1 : fmaf(-t, d[oo][1], p1);
      float r2 = (dot >= 0.f) ? p2 : fmaf(-t, d[oo][2], p2);
      float* dst = hout + (size_t)((b*Co + o)*3) * NP + n;
      dst[0] = r0; dst[NP] = r1; dst[2*NP] = r2;
    }
  }
}

// ------- layer-2 apply (21->42) writing k-packed bf16 hi/lo (64-ch padded) -------------
// Hk3 layout: [b][e][kb=0..7][n][j=0..7], channel c = kb*8+j (c>=42 zero)
__global__ __launch_bounds__(256) void layer_apply2_k(const float* __restrict__ hin, const float* __restrict__ Wf,
    const float* __restrict__ Wd, const float* __restrict__ mi,
    unsigned short* __restrict__ Hk3h, unsigned short* __restrict__ Hk3l){
  const int px = blockIdx.x * 256 + threadIdx.x;
  const int b = px >> 11, n = px & 2047;
  const int kb = blockIdx.y;          // 0..7
  const float* hb = hin + (size_t)b * 21 * 3 * NP + n;
  float r[8][3];
  #pragma unroll
  for (int oo = 0; oo < 8; oo++)
    #pragma unroll
    for (int e = 0; e < 3; e++) r[oo][e] = 0.f;
  if (kb < 6){
    float p[8][3], d[8][3];
    #pragma unroll
    for (int oo = 0; oo < 8; oo++)
      #pragma unroll
      for (int e = 0; e < 3; e++){ p[oo][e] = 0.f; d[oo][e] = 0.f; }
    for (int c = 0; c < 21; c++){
      float h0 = hb[(size_t)(c*3 + 0) * NP];
      float h1 = hb[(size_t)(c*3 + 1) * NP];
      float h2 = hb[(size_t)(c*3 + 2) * NP];
      #pragma unroll
      for (int oo = 0; oo < 8; oo++){
        int o = kb*8 + oo; if (o >= 42) o = 41;
        float wf = Wf[o*21 + c], wd = Wd[o*21 + c];
        p[oo][0] = fmaf(wf, h0, p[oo][0]); p[oo][1] = fmaf(wf, h1, p[oo][1]); p[oo][2] = fmaf(wf, h2, p[oo][2]);
        d[oo][0] = fmaf(wd, h0, d[oo][0]); d[oo][1] = fmaf(wd, h1, d[oo][1]); d[oo][2] = fmaf(wd, h2, d[oo][2]);
      }
    }
    #pragma unroll
    for (int oo = 0; oo < 8; oo++){
      int o = kb*8 + oo;
      if (o < 42){
        float nm = sqrtf(p[oo][0]*p[oo][0] + p[oo][1]*p[oo][1] + p[oo][2]*p[oo][2]) + EPSF;
        float f = (nm - mi[2*o]) * mi[2*o+1] / nm;
        float p0 = p[oo][0]*f, p1 = p[oo][1]*f, p2 = p[oo][2]*f;
        float dot = p0*d[oo][0] + p1*d[oo][1] + p2*d[oo][2];
        float dsq = d[oo][0]*d[oo][0] + d[oo][1]*d[oo][1] + d[oo][2]*d[oo][2];
        float t = dot / (dsq + EPSF);
        r[oo][0] = (dot >= 0.f) ? p0 : fmaf(-t, d[oo][0], p0);
        r[oo][1] = (dot >= 0.f) ? p1 : fmaf(-t, d[oo][1], p1);
        r[oo][2] = (dot >= 0.f) ? p2 : fmaf(-t, d[oo][2], p2);
      }
    }
  }
  #pragma unroll
  for (int e = 0; e < 3; e++){
    unsigned ph[4], pl[4];
    #pragma unroll
    for (int oo = 0; oo < 8; oo++){
      unsigned short hh, ll;
      bsplit(r[oo][e], hh, ll);
      if (!(oo & 1)){ ph[oo>>1] = hh; pl[oo>>1] = ll; }
      else { ph[oo>>1] |= ((unsigned)hh) << 16; pl[oo>>1] |= ((unsigned)ll) << 16; }
    }
    size_t base = ((((size_t)(b*3 + e))*8 + kb) * 2048 + n) * 8;
    *(uint4*)(Hk3h + base) = make_uint4(ph[0], ph[1], ph[2], ph[3]);
    *(uint4*)(Hk3l + base) = make_uint4(pl[0], pl[1], pl[2], pl[3]);
  }
}

__global__ void finalize_stats(const double* __restrict__ sums, float* __restrict__ mi, int Co, double invM){
  int o = blockIdx.x * 64 + threadIdx.x;
  if (o >= Co) return;
  double m = sums[2*o] * invM;
  double v = sums[2*o+1] * invM - m * m;
  if (v < 0.0) v = 0.0;
  mi[2*o] = (float)m;
  mi[2*o+1] = (float)(1.0 / sqrt(v + (double)BNEPS));
}

// ------- split W_pool into k-packed bf16 hi/lo: Wk[cb=0..43][o=0..383][j=0..7] ---------
__global__ __launch_bounds__(256) void wk_kernel(const float* __restrict__ Wp,
    unsigned short* __restrict__ Wkh, unsigned short* __restrict__ Wkl){
  int t = blockIdx.x * 256 + threadIdx.x;
  if (t >= 44*384*8) return;
  int j = t & 7, o = (t >> 3) % 384, cb = t / (384*8);
  int c = cb*8 + j;
  float v = (c < 341 && o < 341) ? Wp[o*341 + c] : 0.f;
  unsigned short h, l;
  bsplit(v, h, l);
  Wkh[t] = h; Wkl[t] = l;
}

// ------- split W3f/W3d into k-packed bf16 hi/lo: Wk3[cb=0..7][o=0..383][j=0..7] --------
__global__ __launch_bounds__(256) void wk3_kernel(const float* __restrict__ W3f, const float* __restrict__ W3d,
    unsigned short* __restrict__ Wfh, unsigned short* __restrict__ Wfl,
    unsigned short* __restrict__ Wdh, unsigned short* __restrict__ Wdl){
  int t = blockIdx.x * 256 + threadIdx.x;
  if (t >= 8*384*8) return;
  int j = t & 7, o = (t >> 3) % 384, cb = t / (384*8);
  int c = cb*8 + j;
  bool ok = (c < 42 && o < 341);
  float vf = ok ? W3f[o*42 + c] : 0.f;
  float vd = ok ? W3d[o*42 + c] : 0.f;
  unsigned short h, l;
  bsplit(vf, h, l); Wfh[t] = h; Wfl[t] = l;
  bsplit(vd, h, l); Wdh[t] = h; Wdl[t] = l;
}

// ------- layer-3 stats via MFMA: P = W3f @ H3 (split-bf16), norms -> sums --------------
// grid (32 n-tiles, 6 o-tiles, 8 b); block 256 = 4 waves x 16 o x 64 n
__global__ __launch_bounds__(256) void stats3_mfma(const unsigned short* __restrict__ Wfh,
    const unsigned short* __restrict__ Wfl, const unsigned short* __restrict__ Hh,
    const unsigned short* __restrict__ Hl, double* __restrict__ sums){
  __shared__ unsigned short sB[2][8][64][8];   // 16 KB
  const int b = blockIdx.z, o0 = blockIdx.y * 64, n0 = blockIdx.x * 64;
  const int t = threadIdx.x, w = t >> 6, l = t & 63;
  const int r = l & 15, g = l >> 4;
  const int wo = o0 + w * 16;
  const int skb = t >> 5, sn = (t & 31) * 2;
  f32x4 acc[3][4];
  #pragma unroll
  for (int e = 0; e < 3; e++)
    #pragma unroll
    for (int nt = 0; nt < 4; nt++) acc[e][nt] = (f32x4)0.f;
  for (int e = 0; e < 3; e++){
    if (e) __syncthreads();
    const uint4* srcH = (const uint4*)(Hh + ((((size_t)(b*3 + e))*8 + skb) * 2048 + n0 + sn) * 8);
    const uint4* srcL = (const uint4*)(Hl + ((((size_t)(b*3 + e))*8 + skb) * 2048 + n0 + sn) * 8);
    uint4 h0 = srcH[0], h1 = srcH[1], l0 = srcL[0], l1 = srcL[1];
    *(uint4*)&sB[0][skb][sn][0] = h0; *(uint4*)&sB[0][skb][sn+1][0] = h1;
    *(uint4*)&sB[1][skb][sn][0] = l0; *(uint4*)&sB[1][skb][sn+1][0] = l1;
    __syncthreads();
    #pragma unroll
    for (int kt = 0; kt < 2; kt++){
      size_t aoff = (((size_t)(kt*4 + g)) * 384 + wo + r) * 8;
      short8 ah = *(const short8*)(Wfh + aoff);
      short8 al = *(const short8*)(Wfl + aoff);
      #pragma unroll
      for (int nt = 0; nt < 4; nt++){
        short8 bh = *(const short8*)&sB[0][kt*4 + g][nt*16 + r][0];
        short8 bl = *(const short8*)&sB[1][kt*4 + g][nt*16 + r][0];
        acc[e][nt] = __builtin_amdgcn_mfma_f32_16x16x32_bf16(ah, bh, acc[e][nt], 0, 0, 0);
        acc[e][nt] = __builtin_amdgcn_mfma_f32_16x16x32_bf16(ah, bl, acc[e][nt], 0, 0, 0);
        acc[e][nt] = __builtin_amdgcn_mfma_f32_16x16x32_bf16(al, bh, acc[e][nt], 0, 0, 0);
      }
    }
  }
  #pragma unroll
  for (int jj = 0; jj < 4; jj++){
    int o = wo + g*4 + jj;
    float s1 = 0.f, s2 = 0.f;
    #pragma unroll
    for (int nt = 0; nt < 4; nt++){
      float p0 = acc[0][nt][jj], p1 = acc[1][nt][jj], p2 = acc[2][nt][jj];
      float nm = sqrtf(p0*p0 + p1*p1 + p2*p2) + EPSF;
      s1 += nm; s2 += nm * nm;
    }
    #pragma unroll
    for (int st = 1; st < 16; st <<= 1){
      s1 += __shfl_xor(s1, st, 64);
      s2 += __shfl_xor(s2, st, 64);
    }
    if (r == 0 && o < 341){
      atomicAdd(&sums[2*o], (double)s1);
      atomicAdd(&sums[2*o+1], (double)s2);
    }
  }
}

// ------- layer-3 apply via MFMA: P,D GEMMs + bn/lrelu + pack into pool input -----------
__global__ __launch_bounds__(256) void apply3_mfma(const unsigned short* __restrict__ Wfh,
    const unsigned short* __restrict__ Wfl, const unsigned short* __restrict__ Wdh,
    const unsigned short* __restrict__ Wdl, const unsigned short* __restrict__ Hh,
    const unsigned short* __restrict__ Hl, const float* __restrict__ mi,
    unsigned short* __restrict__ Hkh, unsigned short* __restrict__ Hkl){
  __shared__ unsigned short sB[2][8][64][8];   // 16 KB
  const int b = blockIdx.z, o0 = blockIdx.y * 64, n0 = blockIdx.x * 64;
  const int t = threadIdx.x, w = t >> 6, l = t & 63;
  const int r = l & 15, g = l >> 4;
  const int wo = o0 + w * 16;
  const int skb = t >> 5, sn = (t & 31) * 2;
  f32x4 accp[3][4], accd[3][4];
  #pragma unroll
  for (int e = 0; e < 3; e++)
    #pragma unroll
    for (int nt = 0; nt < 4; nt++){ accp[e][nt] = (f32x4)0.f; accd[e][nt] = (f32x4)0.f; }
  for (int e = 0; e < 3; e++){
    if (e) __syncthreads();
    const uint4* srcH = (const uint4*)(Hh + ((((size_t)(b*3 + e))*8 + skb) * 2048 + n0 + sn) * 8);
    const uint4* srcL = (const uint4*)(Hl + ((((size_t)(b*3 + e))*8 + skb) * 2048 + n0 + sn) * 8);
    uint4 h0 = srcH[0], h1 = srcH[1], l0 = srcL[0], l1 = srcL[1];
    *(uint4*)&sB[0][skb][sn][0] = h0; *(uint4*)&sB[0][skb][sn+1][0] = h1;
    *(uint4*)&sB[1][skb][sn][0] = l0; *(uint4*)&sB[1][skb][sn+1][0] = l1;
    __syncthreads();
    #pragma unroll
    for (int kt = 0; kt < 2; kt++){
      size_t aoff = (((size_t)(kt*4 + g)) * 384 + wo + r) * 8;
      short8 afh = *(const short8*)(Wfh + aoff);
      short8 afl = *(const short8*)(Wfl + aoff);
      short8 adh = *(const short8*)(Wdh + aoff);
      short8 adl = *(const short8*)(Wdl + aoff);
      #pragma unroll
      for (int nt = 0; nt < 4; nt++){
        short8 bh = *(const short8*)&sB[0][kt*4 + g][nt*16 + r][0];
        short8 bl = *(const short8*)&sB[1][kt*4 + g][nt*16 + r][0];
        accp[e][nt] = __builtin_amdgcn_mfma_f32_16x16x32_bf16(afh, bh, accp[e][nt], 0, 0, 0);
        accp[e][nt] = __builtin_amdgcn_mfma_f32_16x16x32_bf16(afh, bl, accp[e][nt], 0, 0, 0);
        accp[e][nt] = __builtin_amdgcn_mfma_f32_16x16x32_bf16(afl, bh, accp[e][nt], 0, 0, 0);
        accd[e][nt] = __builtin_amdgcn_mfma_f32_16x16x32_bf16(adh, bh, accd[e][nt], 0, 0, 0);
        accd[e][nt] = __builtin_amdgcn_mfma_f32_16x16x32_bf16(adh, bl, accd[e][nt], 0, 0, 0);
        accd[e][nt] = __builtin_amdgcn_mfma_f32_16x16x32_bf16(adl, bh, accd[e][nt], 0, 0, 0);
      }
    }
  }
  const int obase = wo + g*4;
  const int kb = obase >> 3, jo = obase & 7;
  #pragma unroll
  for (int nt = 0; nt < 4; nt++){
    float rr[3][4];
    #pragma unroll
    for (int jj = 0; jj < 4; jj++){
      int o = obase + jj;
      float r0 = 0.f, r1 = 0.f, r2 = 0.f;
      if (o < 341){
        float p0 = accp[0][nt][jj], p1 = accp[1][nt][jj], p2 = accp[2][nt][jj];
        float d0 = accd[0][nt][jj], d1 = accd[1][nt][jj], d2 = accd[2][nt][jj];
        float nm = sqrtf(p0*p0 + p1*p1 + p2*p2) + EPSF;
        float f = (nm - mi[2*o]) * mi[2*o+1] / nm;
        p0 *= f; p1 *= f; p2 *= f;
        float dot = p0*d0 + p1*d1 + p2*d2;
        float dsq = d0*d0 + d1*d1 + d2*d2;
        float tt = dot / (dsq + EPSF);
        r0 = (dot >= 0.f) ? p0 : fmaf(-tt, d0, p0);
        r1 = (dot >= 0.f) ? p1 : fmaf(-tt, d1, p1);
        r2 = (dot >= 0.f) ? p2 : fmaf(-tt, d2, p2);
      }
      rr[0][jj] = r0; rr[1][jj] = r1; rr[2][jj] = r2;
    }
    int n = n0 + nt*16 + r;
    #pragma unroll
    for (int e = 0; e < 3; e++){
      unsigned short h0, l0, h1, l1, h2, l2, h3, l3;
      bsplit(rr[e][0], h0, l0); bsplit(rr[e][1], h1, l1);
      bsplit(rr[e][2], h2, l2); bsplit(rr[e][3], h3, l3);
      unsigned ph0 = (unsigned)h0 | ((unsigned)h1 << 16);
      unsigned ph1 = (unsigned)h2 | ((unsigned)h3 << 16);
      unsigned pl0 = (unsigned)l0 | ((unsigned)l1 << 16);
      unsigned pl1 = (unsigned)l2 | ((unsigned)l3 << 16);
      size_t base = ((((size_t)(b*3 + e))*48 + kb) * 2048 + (size_t)n) * 8 + jo;
      *(uint2*)(Hkh + base) = make_uint2(ph0, ph1);
      *(uint2*)(Hkl + base) = make_uint2(pl0, pl1);
    }
  }
}

// ------------- pool over N via split-bf16 MFMA: D = Wpool @ H; dot; argmax -------------
__global__ __launch_bounds__(256) void pool_mfma(const unsigned short* __restrict__ Wkh,
    const unsigned short* __restrict__ Wkl, const unsigned short* __restrict__ Hkh,
    const unsigned short* __restrict__ Hkl, unsigned long long* __restrict__ packed){
  __shared__ unsigned short sB[2][2][4][64][8];   // 16 KB
  const int b = blockIdx.z, o0 = blockIdx.y * 128, n0 = blockIdx.x * 64;
  const int t = threadIdx.x, w = t >> 6, l = t & 63;
  const int wo = o0 + w * 32;
  const int r = l & 15, g = l >> 4;
  const int skb = t >> 6, sn = t & 63;
  const int ktw = wo >> 5;

  f32x4 acc[2][4], dotv[2][4], hval[2][4];
  #pragma unroll
  for (int s = 0; s < 2; s++)
    #pragma unroll
    for (int nt = 0; nt < 4; nt++){ dotv[s][nt] = (f32x4)0.f; hval[s][nt] = (f32x4)0.f; }

  auto gsrc = [&](const unsigned short* base, int e, int kt) -> const uint4* {
    return (const uint4*)(base + ((((size_t)(b*3 + e))*48 + (size_t)(kt*4 + skb)) * 2048 + n0 + sn) * 8);
  };

  uint4 rg[2];
  rg[0] = *gsrc(Hkh, 0, 0);
  rg[1] = *gsrc(Hkl, 0, 0);

  for (int ek = 0; ek < 33; ek++){
    const int e = ek / 11, kt = ek - e*11, buf = ek & 1;
    *(uint4*)&sB[buf][0][skb][sn][0] = rg[0];
    *(uint4*)&sB[buf][1][skb][sn][0] = rg[1];
    __syncthreads();
    if (ek < 32){
      int e2 = (ek+1) / 11, kt2 = (ek+1) - e2*11;
      rg[0] = *gsrc(Hkh, e2, kt2);
      rg[1] = *gsrc(Hkl, e2, kt2);
    }
    if (kt == 0){
      #pragma unroll
      for (int s = 0; s < 2; s++)
        #pragma unroll
        for (int nt = 0; nt < 4; nt++) acc[s][nt] = (f32x4)0.f;
    }
    short8 ah[2], al[2];
    #pragma unroll
    for (int s = 0; s < 2; s++){
      size_t aoff = (((size_t)(kt*4 + g)) * 384 + (wo + s*16 + r)) * 8;
      ah[s] = *(const short8*)(Wkh + aoff);
      al[s] = *(const short8*)(Wkl + aoff);
    }
    #pragma unroll
    for (int nt = 0; nt < 4; nt++){
      short8 bh = *(const short8*)&sB[buf][0][g][nt*16 + r][0];
      short8 bl = *(const short8*)&sB[buf][1][g][nt*16 + r][0];
      #pragma unroll
      for (int s = 0; s < 2; s++){
        acc[s][nt] = __builtin_amdgcn_mfma_f32_16x16x32_bf16(ah[s], bh, acc[s][nt], 0, 0, 0);
        acc[s][nt] = __builtin_amdgcn_mfma_f32_16x16x32_bf16(ah[s], bl, acc[s][nt], 0, 0, 0);
        acc[s][nt] = __builtin_amdgcn_mfma_f32_16x16x32_bf16(al[s], bh, acc[s][nt], 0, 0, 0);
      }
    }
    if (kt == ktw){
      #pragma unroll
      for (int s = 0; s < 2; s++){
        #pragma unroll
        for (int jj = 0; jj < 4; jj++){
          int oin = s*16 + g*4 + jj;
          #pragma unroll
          for (int nt = 0; nt < 4; nt++){
            hval[s][nt][jj] = bf2f(sB[buf][0][oin>>3][nt*16 + r][oin&7])
                            + bf2f(sB[buf][1][oin>>3][nt*16 + r][oin&7]);
          }
        }
      }
    }
    __syncthreads();
    if (kt == 10){
      #pragma unroll
      for (int s = 0; s < 2; s++)
        #pragma unroll
        for (int nt = 0; nt < 4; nt++)
          #pragma unroll
          for (int jj = 0; jj < 4; jj++)
            dotv[s][nt][jj] += acc[s][nt][jj] * hval[s][nt][jj];
    }
  }
  #pragma unroll
  for (int s = 0; s < 2; s++){
    #pragma unroll
    for (int j = 0; j < 4; j++){
      int o = wo + s*16 + g*4 + j;
      unsigned long long best = 0;
      #pragma unroll
      for (int nt = 0; nt < 4; nt++){
        int n = n0 + nt*16 + r;
        unsigned long long pk = ((unsigned long long)ordf(dotv[s][nt][j]) << 32) | (unsigned)(2047 - n);
        if (pk > best) best = pk;
      }
      #pragma unroll
      for (int st = 1; st < 16; st <<= 1){
        unsigned long long ob = __shfl_xor(best, st, 64);
        if (ob > best) best = ob;
      }
      if (r == 0 && o < 341) atomicMax(&packed[b*341 + o], best);
    }
  }
}

__global__ void pool_gather(const unsigned long long* __restrict__ packed,
                            const unsigned short* __restrict__ Hkh, const unsigned short* __restrict__ Hkl,
                            float* __restrict__ pooled){
  int t = blockIdx.x * 256 + threadIdx.x;
  if (t >= BATCH * 341) return;
  int n = 2047 - (int)(packed[t] & 0xffffffffu);
  int b = t / 341, o = t % 341;
  #pragma unroll
  for (int e = 0; e < 3; e++){
    size_t hb = ((((size_t)(b*3 + e))*48 + (o >> 3)) * 2048 + n) * 8 + (o & 7);
    pooled[t*3 + e] = bf2f(Hkh[hb]) + bf2f(Hkl[hb]);
  }
}

// -------- fully-connected VN layer (B=8 pixels, per-channel bn over B) -----------------
__global__ __launch_bounds__(64) void flayer(const float* __restrict__ in, const float* __restrict__ Wf,
    const float* __restrict__ Wd, float* __restrict__ out, int Cin, int Co){
  int o = blockIdx.x, lane = threadIdx.x;
  float pv[24], dv[24];
  #pragma unroll
  for (int be = 0; be < 24; be++){ pv[be] = 0.f; dv[be] = 0.f; }
  for (int c = lane; c < Cin; c += 64){
    float wf = Wf[o*Cin + c], wd = Wd[o*Cin + c];
    #pragma unroll
    for (int bb = 0; bb < 8; bb++){
      #pragma unroll
      for (int e = 0; e < 3; e++){
        float hv = in[(bb*Cin + c)*3 + e];
        pv[bb*3+e] = fmaf(wf, hv, pv[bb*3+e]);
        dv[bb*3+e] = fmaf(wd, hv, dv[bb*3+e]);
      }
    }
  }
  #pragma unroll
  for (int be = 0; be < 24; be++){
    #pragma unroll
    for (int st = 1; st < 64; st <<= 1){
      pv[be] += __shfl_xor(pv[be], st, 64);
      dv[be] += __shfl_xor(dv[be], st, 64);
    }
  }
  float nm[8], dotb[8], dsqb[8];
  float mean = 0.f;
  #pragma unroll
  for (int bb = 0; bb < 8; bb++){
    nm[bb] = sqrtf(pv[bb*3]*pv[bb*3] + pv[bb*3+1]*pv[bb*3+1] + pv[bb*3+2]*pv[bb*3+2]) + EPSF;
    mean += nm[bb];
  }
  mean *= 0.125f;
  float var = 0.f;
  #pragma unroll
  for (int bb = 0; bb < 8; bb++){ float dvv = nm[bb] - mean; var += dvv * dvv; }
  var *= 0.125f;
  float istd = 1.f / sqrtf(var + BNEPS);
  #pragma unroll
  for (int bb = 0; bb < 8; bb++){
    float f = (nm[bb] - mean) * istd / nm[bb];
    dotb[bb] = f * (pv[bb*3]*dv[bb*3] + pv[bb*3+1]*dv[bb*3+1] + pv[bb*3+2]*dv[bb*3+2]);
    dsqb[bb] = dv[bb*3]*dv[bb*3] + dv[bb*3+1]*dv[bb*3+1] + dv[bb*3+2]*dv[bb*3+2];
  }
  #pragma unroll
  for (int be = 0; be < 24; be++){
    if (lane == be){
      int bb = be / 3;
      float f = (nm[bb] - mean) * istd / nm[bb];
      float pe = pv[be] * f;
      float t = dotb[bb] / (dsqb[bb] + EPSF);
      float res = (dotb[bb] >= 0.f) ? pe : fmaf(-t, dv[be], pe);
      out[(bb*Co + o)*3 + (be % 3)] = res;
    }
  }
}

__global__ void final_lin(const float* __restrict__ in, const float* __restrict__ W, float* __restrict__ out){
  int t = threadIdx.x;
  if (t >= 72) return;
  int b = t / 9, o = (t % 9) / 3, e = t % 3;
  float s = 0.f;
  for (int c = 0; c < 85; c++) s = fmaf(W[o*85 + c], in[(b*85 + c)*3 + e], s);
  out[t] = s;
}

// --------------------------------- launcher -------------------------------------------
extern "C" void kernel_launch(void* const* d_in, const int* in_sizes, int n_in,
                              void* d_out, int out_size, void* d_ws, size_t ws_size,
                              hipStream_t stream){
  const float* x   = (const float*)d_in[0];
  const float* Wpf = (const float*)d_in[1];
  const float* Wpd = (const float*)d_in[2];
  const float* Wg  = (const float*)d_in[3];
  const float* W1f = (const float*)d_in[4];
  const float* W1d = (const float*)d_in[5];
  const float* W2f = (const float*)d_in[6];
  const float* W2d = (const float*)d_in[7];
  const float* W3f = (const float*)d_in[8];
  const float* W3d = (const float*)d_in[9];
  const float* Wpool = (const float*)d_in[10];
  const float* Wf1f = (const float*)d_in[11];
  const float* Wf1d = (const float*)d_in[12];
  const float* Wf2f = (const float*)d_in[13];
  const float* Wf2d = (const float*)d_in[14];
  const float* Wf3  = (const float*)d_in[15];
  float* out = (float*)d_out;

  char* ws = (char*)d_ws;
  size_t off = 0;
  int*   idx  = (int*)(ws + off);             off += (size_t)BATCH*NP*KNN*4;
  unsigned long long* packedGF = (unsigned long long*)(ws + off); off += (size_t)BATCH*NP*21*8;
  float* h1  = (float*)(ws + off);            off += (size_t)BATCH*21*3*NP*4;
  float* h2  = (float*)(ws + off);            off += (size_t)BATCH*21*3*NP*4;
  unsigned short* Hk3h = (unsigned short*)(ws + off); off += (size_t)BATCH*3*8*NP*8*2;
  unsigned short* Hk3l = (unsigned short*)(ws + off); off += (size_t)BATCH*3*8*NP*8*2;
  unsigned short* Hkh = (unsigned short*)(ws + off); off += (size_t)BATCH*3*48*NP*8*2;
  unsigned short* Hkl = (unsigned short*)(ws + off); off += (size_t)BATCH*3*48*NP*8*2;
  unsigned short* Wkh = (unsigned short*)(ws + off); off += (size_t)44*384*8*2;
  unsigned short* Wkl = (unsigned short*)(ws + off); off += (size_t)44*384*8*2;
  unsigned short* Wk3fh = (unsigned short*)(ws + off); off += (size_t)8*384*8*2;
  unsigned short* Wk3fl = (unsigned short*)(ws + off); off += (size_t)8*384*8*2;
  unsigned short* Wk3dh = (unsigned short*)(ws + off); off += (size_t)8*384*8*2;
  unsigned short* Wk3dl = (unsigned short*)(ws + off); off += (size_t)8*384*8*2;
  char*  zbase = ws + off;
  double* sums_gf = (double*)(ws + off);      off += 8192;
  double* sums_l1 = (double*)(ws + off);      off += 8192;
  double* sums_l2 = (double*)(ws + off);      off += 8192;
  double* sums_l3 = (double*)(ws + off);      off += 8192;
  unsigned long long* packed = (unsigned long long*)(ws + off); off += 24576;
  size_t zbytes = (ws + off) - zbase;
  float* mi_gf = (float*)(ws + off);          off += 1024;
  float* mi_l1 = (float*)(ws + off);          off += 1024;
  float* mi_l2 = (float*)(ws + off);          off += 1024;
  float* mi_l3 = (float*)(ws + off);          off += 4096;
  float* pooled = (float*)(ws + off);         off += (size_t)BATCH*341*3*4 + 32;
  float* h5 = (float*)(ws + off);             off += (size_t)BATCH*170*3*4 + 32;
  float* h6 = (float*)(ws + off);             off += (size_t)BATCH*85*3*4 + 32;

  hipMemsetAsync(zbase, 0, zbytes, stream);

  knn_kernel<<<BATCH*NP/8, 256, 0, stream>>>(x, idx);
  wk_kernel<<<(44*384*8 + 255)/256, 256, 0, stream>>>(Wpool, Wkh, Wkl);
  wk3_kernel<<<(8*384*8 + 255)/256, 256, 0, stream>>>(W3f, W3d, Wk3fh, Wk3fl, Wk3dh, Wk3dl);

  gf_stats<<<256, 256, 0, stream>>>(x, idx, Wpf, sums_gf);
  finalize_stats<<<1, 64, 0, stream>>>(sums_gf, mi_gf, 21, 1.0 / (double)(BATCH*NP*KNN));
  gf_applypool3<<<BATCH*NP/8, 320, 0, stream>>>(x, idx, Wpf, Wpd, Wg, mi_gf, packedGF);
  gf_gather<<<(BATCH*NP*21 + 255)/256, 256, 0, stream>>>(x, idx, Wpf, Wpd, mi_gf, packedGF, h1);

  layer_stats2<21><<<dim3(16,3), 256, 0, stream>>>(h1, W1f, sums_l1, 21);
  finalize_stats<<<1, 64, 0, stream>>>(sums_l1, mi_l1, 21, 1.0 / (double)(BATCH*NP));
  layer_apply2<21><<<dim3(64,3), 256, 0, stream>>>(h1, W1f, W1d, mi_l1, h2, 21);

  layer_stats2<21><<<dim3(16,6), 256, 0, stream>>>(h2, W2f, sums_l2, 42);
  finalize_stats<<<1, 64, 0, stream>>>(sums_l2, mi_l2, 42, 1.0 / (double)(BATCH*NP));
  layer_apply2_k<<<dim3(64,8), 256, 0, stream>>>(h2, W2f, W2d, mi_l2, Hk3h, Hk3l);

  stats3_mfma<<<dim3(32, 6, BATCH), 256, 0, stream>>>(Wk3fh, Wk3fl, Hk3h, Hk3l, sums_l3);
  finalize_stats<<<6, 64, 0, stream>>>(sums_l3, mi_l3, 341, 1.0 / (double)(BATCH*NP));
  apply3_mfma<<<dim3(32, 6, BATCH), 256, 0, stream>>>(Wk3fh, Wk3fl, Wk3dh, Wk3dl, Hk3h, Hk3l, mi_l3, Hkh, Hkl);

  pool_mfma<<<dim3(32, 3, BATCH), 256, 0, stream>>>(Wkh, Wkl, Hkh, Hkl, packed);
  pool_gather<<<(BATCH*341 + 255)/256, 256, 0, stream>>>(packed, Hkh, Hkl, pooled);

  flayer<<<170, 64, 0, stream>>>(pooled, Wf1f, Wf1d, h5, 341, 170);
  flayer<<<85, 64, 0, stream>>>(h5, Wf2f, Wf2d, h6, 170, 85);
  final_lin<<<1, 128, 0, stream>>>(h6, Wf3, out);
}